// Round 1
// baseline (536.776 us; speedup 1.0000x reference)
//
#include <hip/hip_runtime.h>
#include <hip/hip_fp16.h>

// SpatioTemporalFusion: all attention has seqlen 1 -> softmax==1 -> MHA(xq,xk,xv)
// reduces to (xv@vw^T+vb)@ow^T+ob. Q/K projections are dead. Network is 10 GEMMs
// [16384,1024]x[1024,1024] (f1 has K=2048) + final LayerNorm.
//
// GEMM: m97-structure (128x128 tile, BK=32, global_load_lds width=16,
// mfma_f32_16x16x32_f16, 4 waves 2x2 each 64x64). f16 chosen over bf16 for
// 4x mantissa accuracy at the same MFMA rate.

typedef _Float16 half8 __attribute__((ext_vector_type(8)));
typedef float floatx4 __attribute__((ext_vector_type(4)));

#define GLOBAL_AS __attribute__((address_space(1)))
#define LDS_AS __attribute__((address_space(3)))

#define NB 16384          // batch rows
#define FDIM 1024

// ---------------- fp32 -> fp16 convert (vectorized, grid-stride) ----------------
__global__ __launch_bounds__(256) void cvt_f32_f16(const float* __restrict__ in,
                                                   _Float16* __restrict__ out,
                                                   long n4) {
  long i = (long)blockIdx.x * blockDim.x + threadIdx.x;
  long stride = (long)gridDim.x * blockDim.x;
  for (; i < n4; i += stride) {
    float4 v = reinterpret_cast<const float4*>(in)[i];
    union { _Float16 h[4]; short4 s; } u;
    u.h[0] = (_Float16)v.x; u.h[1] = (_Float16)v.y;
    u.h[2] = (_Float16)v.z; u.h[3] = (_Float16)v.w;
    reinterpret_cast<short4*>(out)[i] = u.s;
  }
}

// ---------------- GEMM: C[M,N] = A[M,K] @ W[N,K]^T + bias (opt relu) ----------------
// A, W fp16 row-major (stride K). C stored fp16 with row stride ldc.
template <int RELU>
__global__ __launch_bounds__(256, 2) void gemm_f16(
    const _Float16* __restrict__ A, const _Float16* __restrict__ W,
    const float* __restrict__ bias, _Float16* __restrict__ C,
    int M, int N, int K, int ldc) {
  __shared__ __align__(16) _Float16 As[128 * 32];
  __shared__ __align__(16) _Float16 Ws[128 * 32];

  const int t = threadIdx.x;
  const int lane = t & 63;
  const int wave = t >> 6;
  const int wr = wave >> 1;       // wave row (0..1) -> 64-row slab
  const int wc = wave & 1;        // wave col (0..1) -> 64-col slab

  // XCD-aware swizzle (grid is a multiple of 8 here: M/128*N/128 = 128*8 = 1024)
  const int nwg = gridDim.x;
  int bid = blockIdx.x;
  int swz = (bid & 7) * (nwg >> 3) + (bid >> 3);
  const int nTilesN = N >> 7;
  const int bm = swz / nTilesN;
  const int bn = swz % nTilesN;
  const int m0 = bm << 7, n0 = bn << 7;

  floatx4 acc[4][4] = {};

  // staging addresses: thread t stages 16B = 8 halves; issue i covers rows i*64..i*64+63
  const int srow = t >> 2;             // 0..63
  const int scol = (t & 3) * 8;        // 0,8,16,24
  const _Float16* Ag = A + (long)(m0 + srow) * K + scol;
  const _Float16* Wg = W + (long)(n0 + srow) * K + scol;

  const int frow = lane & 15;          // fragment row/col within 16
  const int fk = (lane >> 4) * 8;      // k-offset within BK=32

  for (int k0 = 0; k0 < K; k0 += 32) {
#pragma unroll
    for (int i = 0; i < 2; ++i) {
      __builtin_amdgcn_global_load_lds(
          (const GLOBAL_AS void*)(Ag + (long)i * 64 * K + k0),
          (LDS_AS void*)(&As[i * 2048 + t * 8]), 16, 0, 0);
      __builtin_amdgcn_global_load_lds(
          (const GLOBAL_AS void*)(Wg + (long)i * 64 * K + k0),
          (LDS_AS void*)(&Ws[i * 2048 + t * 8]), 16, 0, 0);
    }
    __syncthreads();

    half8 a[4], b[4];
#pragma unroll
    for (int r = 0; r < 4; ++r)
      a[r] = *(const half8*)&As[(wr * 64 + r * 16 + frow) * 32 + fk];
#pragma unroll
    for (int c = 0; c < 4; ++c)
      b[c] = *(const half8*)&Ws[(wc * 64 + c * 16 + frow) * 32 + fk];

#pragma unroll
    for (int r = 0; r < 4; ++r)
#pragma unroll
      for (int c = 0; c < 4; ++c)
        acc[r][c] = __builtin_amdgcn_mfma_f32_16x16x32_f16(a[r], b[c], acc[r][c], 0, 0, 0);
    __syncthreads();
  }

  // epilogue: C/D layout col = lane&15, row = (lane>>4)*4 + j  [m89-verified]
  const int rbase = lane >> 4;
#pragma unroll
  for (int c = 0; c < 4; ++c) {
    const int col = n0 + wc * 64 + c * 16 + frow;
    const float bv = bias[col];
#pragma unroll
    for (int r = 0; r < 4; ++r) {
#pragma unroll
      for (int j = 0; j < 4; ++j) {
        int row = m0 + wr * 64 + r * 16 + rbase * 4 + j;
        float v = acc[r][c][j] + bv;
        if (RELU) v = fmaxf(v, 0.f);
        C[(long)row * ldc + col] = (_Float16)v;
      }
    }
  }
}

// ---------------- LayerNorm over last dim (1024), f16 in, f32 out ----------------
__global__ __launch_bounds__(256) void ln_f16(const _Float16* __restrict__ x,
                                              const float* __restrict__ g,
                                              const float* __restrict__ b,
                                              float* __restrict__ out) {
  const int row = blockIdx.x;
  const int t = threadIdx.x;
  const _Float16* xr = x + (size_t)row * FDIM;
  short4 raw = reinterpret_cast<const short4*>(xr)[t];
  union { short4 s; _Float16 h[4]; } u;
  u.s = raw;
  float v0 = (float)u.h[0], v1 = (float)u.h[1], v2 = (float)u.h[2], v3 = (float)u.h[3];
  float s = v0 + v1 + v2 + v3;
  float q = v0 * v0 + v1 * v1 + v2 * v2 + v3 * v3;
#pragma unroll
  for (int off = 32; off > 0; off >>= 1) {
    s += __shfl_down(s, off);
    q += __shfl_down(q, off);
  }
  __shared__ float ss[4], qs[4];
  int wave = t >> 6, lane = t & 63;
  if (lane == 0) { ss[wave] = s; qs[wave] = q; }
  __syncthreads();
  float S = ss[0] + ss[1] + ss[2] + ss[3];
  float Q = qs[0] + qs[1] + qs[2] + qs[3];
  float mu = S * (1.f / FDIM);
  float var = Q * (1.f / FDIM) - mu * mu;
  float rs = rsqrtf(var + 1e-5f);
  int c = t * 4;
  float4 o;
  o.x = (v0 - mu) * rs * g[c + 0] + b[c + 0];
  o.y = (v1 - mu) * rs * g[c + 1] + b[c + 1];
  o.z = (v2 - mu) * rs * g[c + 2] + b[c + 2];
  o.w = (v3 - mu) * rs * g[c + 3] + b[c + 3];
  reinterpret_cast<float4*>(out + (size_t)row * FDIM)[t] = o;
}

// ---------------- launch ----------------
extern "C" void kernel_launch(void* const* d_in, const int* in_sizes, int n_in,
                              void* d_out, int out_size, void* d_ws, size_t ws_size,
                              hipStream_t stream) {
  const float* spatial  = (const float*)d_in[0];
  const float* temporal = (const float*)d_in[1];
  const float* sp_w = (const float*)d_in[2];
  const float* sp_b = (const float*)d_in[3];
  const float* tp_w = (const float*)d_in[4];
  const float* tp_b = (const float*)d_in[5];
  // st: q(6,7) k(8,9) v(10,11) o(12,13) — q/k unused (seqlen-1 softmax == 1)
  const float* st_vw = (const float*)d_in[10];
  const float* st_vb = (const float*)d_in[11];
  const float* st_ow = (const float*)d_in[12];
  const float* st_ob = (const float*)d_in[13];
  const float* ts_vw = (const float*)d_in[18];
  const float* ts_vb = (const float*)d_in[19];
  const float* ts_ow = (const float*)d_in[20];
  const float* ts_ob = (const float*)d_in[21];
  const float* sa_vw = (const float*)d_in[26];
  const float* sa_vb = (const float*)d_in[27];
  const float* sa_ow = (const float*)d_in[28];
  const float* sa_ob = (const float*)d_in[29];
  const float* f1_w = (const float*)d_in[30];
  const float* f1_b = (const float*)d_in[31];
  const float* f2_w = (const float*)d_in[32];
  const float* f2_b = (const float*)d_in[33];
  const float* ln_g = (const float*)d_in[34];
  const float* ln_b = (const float*)d_in[35];

  // workspace layout (halves)
  _Float16* ws = (_Float16*)d_ws;
  size_t off = 0;
  auto alloc = [&](size_t n) { _Float16* p = ws + off; off += n; return p; };
  const size_t WSZ = 1024 * 1024;       // 1Mi halves
  const size_t ACT = (size_t)NB * 1024; // 16Mi halves
  _Float16* w_sp  = alloc(WSZ);
  _Float16* w_tp  = alloc(WSZ);
  _Float16* w_stv = alloc(WSZ);
  _Float16* w_sto = alloc(WSZ);
  _Float16* w_tsv = alloc(WSZ);
  _Float16* w_tso = alloc(WSZ);
  _Float16* w_sav = alloc(WSZ);
  _Float16* w_sao = alloc(WSZ);
  _Float16* w_f1  = alloc(2 * WSZ);
  _Float16* w_f2  = alloc(WSZ);
  _Float16* buf0  = alloc(ACT);       // sp16 -> a1 -> b1
  _Float16* buf1  = alloc(ACT);       // tp16 -> a2 -> fused2
  _Float16* buf2  = alloc(ACT);       // sp_proj -> h
  _Float16* buf3  = alloc(ACT);       // tp_proj -> fused
  _Float16* cat   = alloc(2 * ACT);   // [s_att | t_att]

  auto cvt = [&](const float* src, _Float16* dst, long n) {
    cvt_f32_f16<<<1024, 256, 0, stream>>>(src, dst, n / 4);
  };
  auto gemm = [&](const _Float16* A, const _Float16* W, const float* bias,
                  _Float16* C, int M, int N, int K, int ldc, bool relu) {
    dim3 grid((M / 128) * (N / 128)), block(256);
    if (relu)
      gemm_f16<1><<<grid, block, 0, stream>>>(A, W, bias, C, M, N, K, ldc);
    else
      gemm_f16<0><<<grid, block, 0, stream>>>(A, W, bias, C, M, N, K, ldc);
  };

  // convert inputs + live weights to f16
  cvt(spatial, buf0, (long)NB * 1024);
  cvt(temporal, buf1, (long)NB * 1024);
  cvt(sp_w, w_sp, WSZ);
  cvt(tp_w, w_tp, WSZ);
  cvt(st_vw, w_stv, WSZ);
  cvt(st_ow, w_sto, WSZ);
  cvt(ts_vw, w_tsv, WSZ);
  cvt(ts_ow, w_tso, WSZ);
  cvt(sa_vw, w_sav, WSZ);
  cvt(sa_ow, w_sao, WSZ);
  cvt(f1_w, w_f1, 2 * WSZ);
  cvt(f2_w, w_f2, WSZ);

  // sp_proj = spatial@sp_w^T ; tp_proj = temporal@tp_w^T
  gemm(buf0, w_sp, sp_b, buf2, NB, FDIM, FDIM, FDIM, false);
  gemm(buf1, w_tp, tp_b, buf3, NB, FDIM, FDIM, FDIM, false);
  // a1 = tp_proj@st_vw^T (value path of s_att; Q/K dead) ; a2 = sp_proj@ts_vw^T
  gemm(buf3, w_stv, st_vb, buf0, NB, FDIM, FDIM, FDIM, false);
  gemm(buf2, w_tsv, ts_vb, buf1, NB, FDIM, FDIM, FDIM, false);
  // s_att -> cat[:, :1024] ; t_att -> cat[:, 1024:]
  gemm(buf0, w_sto, st_ob, cat, NB, FDIM, FDIM, 2 * FDIM, false);
  gemm(buf1, w_tso, ts_ob, cat + FDIM, NB, FDIM, FDIM, 2 * FDIM, false);
  // h = relu(cat@f1^T) ; fused = h@f2^T
  gemm(cat, w_f1, f1_b, buf2, NB, FDIM, 2 * FDIM, FDIM, true);
  gemm(buf2, w_f2, f2_b, buf3, NB, FDIM, FDIM, FDIM, false);
  // self-attn value path: b1 = fused@sa_vw^T ; fused2 = b1@sa_ow^T
  gemm(buf3, w_sav, sa_vb, buf0, NB, FDIM, FDIM, FDIM, false);
  gemm(buf0, w_sao, sa_ob, buf1, NB, FDIM, FDIM, FDIM, false);
  // LayerNorm
  ln_f16<<<NB, 256, 0, stream>>>(buf1, ln_g, ln_b, (float*)d_out);
}

// Round 2
// 286.922 us; speedup vs baseline: 1.8708x; 1.8708x over previous
//
#include <hip/hip_runtime.h>
#include <hip/hip_fp16.h>

// SpatioTemporalFusion — fully folded form.
// seqlen==1 => softmax==1 => attention == (x@vw^T+vb)@ow^T+ob (affine).
// All affine chains composed offline (on-device, tiny weight GEMMs):
//   h      = relu(Xcat @ Wh^T + bh),  Xcat=[temporal|spatial] (16384x2048)
//            Wh = [f1a@st_ow@st_vw@tp_w | f1b@ts_ow@ts_vw@sp_w]  (1024x2048)
//   out    = LN(h @ W2^T + b2),       W2 = sa_ow@sa_vw@f2_w      (1024x1024)
// Only 2 big GEMMs (103 GFLOP) survive of the original 10 (344 GFLOP).

typedef _Float16 half8 __attribute__((ext_vector_type(8)));
typedef float floatx4 __attribute__((ext_vector_type(4)));

#define GLOBAL_AS __attribute__((address_space(1)))
#define LDS_AS __attribute__((address_space(3)))

#define NB 16384
#define FDIM 1024

// ---------- strided f32 -> f16 convert; cols fixed at 1024 (256 float4/row) ----------
__global__ __launch_bounds__(256) void cvt_strided(const float* __restrict__ in, long ld_in,
                                                   _Float16* __restrict__ out, long ld_out,
                                                   long n4) {
  long i = (long)blockIdx.x * blockDim.x + threadIdx.x;
  long stride = (long)gridDim.x * blockDim.x;
  for (; i < n4; i += stride) {
    long row = i >> 8;          // cols/4 == 256
    long c4 = i & 255;
    float4 v = *reinterpret_cast<const float4*>(in + row * ld_in + c4 * 4);
    union { _Float16 h[4]; short4 s; } u;
    u.h[0] = (_Float16)v.x; u.h[1] = (_Float16)v.y;
    u.h[2] = (_Float16)v.z; u.h[3] = (_Float16)v.w;
    *reinterpret_cast<short4*>(out + row * ld_out + c4 * 4) = u.s;
  }
}

// ---------- batched 1024x1024 transpose + f32->f16 convert ----------
struct TP8 { const float* in[8]; _Float16* out[8]; };
__global__ __launch_bounds__(256) void transpose_cvt(TP8 args) {
  __shared__ float tile[32][33];
  const float* in = args.in[blockIdx.z];
  _Float16* out = args.out[blockIdx.z];
  const int bx = blockIdx.x * 32;   // input col base
  const int by = blockIdx.y * 32;   // input row base
  const int tx = threadIdx.x & 31;
  const int ty = threadIdx.x >> 5;  // 0..7
#pragma unroll
  for (int r = 0; r < 32; r += 8)
    tile[ty + r][tx] = in[(long)(by + ty + r) * 1024 + bx + tx];
  __syncthreads();
#pragma unroll
  for (int r = 0; r < 32; r += 8)
    out[(long)(bx + ty + r) * 1024 + by + tx] = (_Float16)tile[tx][ty + r];
}

// ---------- batched matvec: y = W@x + add  (W f32, 1024x1024, row stride ld) ----------
struct MV3 {
  const float* W[3]; const float* x[3]; const float* add[3]; float* y[3]; long ld[3];
};
__global__ __launch_bounds__(256) void matvec3(MV3 a) {
  const int b = blockIdx.y;
  const int row = blockIdx.x * 4 + (threadIdx.x >> 6);
  const int lane = threadIdx.x & 63;
  const float* wr = a.W[b] + (long)row * a.ld[b];
  const float* xv = a.x[b];
  float s = 0.f;
#pragma unroll
  for (int j = 0; j < 4; ++j) {
    float4 w4 = *reinterpret_cast<const float4*>(wr + (lane + 64 * j) * 4);
    float4 x4 = *reinterpret_cast<const float4*>(xv + (lane + 64 * j) * 4);
    s += w4.x * x4.x + w4.y * x4.y + w4.z * x4.z + w4.w * x4.w;
  }
#pragma unroll
  for (int off = 32; off > 0; off >>= 1) s += __shfl_down(s, off);
  if (lane == 0) {
    const float* ad = a.add[b];
    a.y[b][row] = s + (ad ? ad[row] : 0.f);
  }
}

// ---------- GEMM: C[M,N] = A[M,K] @ W[N,K]^T + bias (opt relu), batched over y ----------
struct GemmArgs { const _Float16* A; const _Float16* W; const float* bias; _Float16* C; int ldc; };
struct GB3 { GemmArgs g[3]; };

template <int RELU>
__global__ __launch_bounds__(256, 2) void gemm_f16(GB3 args, int M, int N, int K) {
  __shared__ __align__(16) _Float16 As[128 * 32];
  __shared__ __align__(16) _Float16 Ws[128 * 32];

  const GemmArgs ga = args.g[blockIdx.y];

  const int t = threadIdx.x;
  const int lane = t & 63;
  const int wave = t >> 6;
  const int wr = wave >> 1;
  const int wc = wave & 1;

  // XCD-aware swizzle (all grids here are multiples of 8)
  const int nwg = gridDim.x;
  const int bid = blockIdx.x;
  const int swz = (bid & 7) * (nwg >> 3) + (bid >> 3);
  const int nTilesN = N >> 7;
  const int m0 = (swz / nTilesN) << 7;
  const int n0 = (swz % nTilesN) << 7;

  floatx4 acc[4][4] = {};

  const int srow = t >> 2;
  const int scol = (t & 3) * 8;
  const _Float16* Ag = ga.A + (long)(m0 + srow) * K + scol;
  const _Float16* Wg = ga.W + (long)(n0 + srow) * K + scol;

  const int frow = lane & 15;
  const int fk = (lane >> 4) * 8;

  for (int k0 = 0; k0 < K; k0 += 32) {
#pragma unroll
    for (int i = 0; i < 2; ++i) {
      __builtin_amdgcn_global_load_lds(
          (const GLOBAL_AS void*)(Ag + (long)i * 64 * K + k0),
          (LDS_AS void*)(&As[i * 2048 + t * 8]), 16, 0, 0);
      __builtin_amdgcn_global_load_lds(
          (const GLOBAL_AS void*)(Wg + (long)i * 64 * K + k0),
          (LDS_AS void*)(&Ws[i * 2048 + t * 8]), 16, 0, 0);
    }
    __syncthreads();

    half8 a[4], b[4];
#pragma unroll
    for (int r = 0; r < 4; ++r)
      a[r] = *(const half8*)&As[(wr * 64 + r * 16 + frow) * 32 + fk];
#pragma unroll
    for (int c = 0; c < 4; ++c)
      b[c] = *(const half8*)&Ws[(wc * 64 + c * 16 + frow) * 32 + fk];

#pragma unroll
    for (int r = 0; r < 4; ++r)
#pragma unroll
      for (int c = 0; c < 4; ++c)
        acc[r][c] = __builtin_amdgcn_mfma_f32_16x16x32_f16(a[r], b[c], acc[r][c], 0, 0, 0);
    __syncthreads();
  }

  // epilogue: C/D layout col = lane&15, row = (lane>>4)*4 + j  [m89-verified]
  const int rbase = lane >> 4;
#pragma unroll
  for (int c = 0; c < 4; ++c) {
    const int col = n0 + wc * 64 + c * 16 + frow;
    const float bv = ga.bias ? ga.bias[col] : 0.f;
#pragma unroll
    for (int r = 0; r < 4; ++r) {
#pragma unroll
      for (int j = 0; j < 4; ++j) {
        int row = m0 + wr * 64 + r * 16 + rbase * 4 + j;
        float v = acc[r][c][j] + bv;
        if (RELU) v = fmaxf(v, 0.f);
        ga.C[(long)row * ga.ldc + col] = (_Float16)v;
      }
    }
  }
}

// ---------- LayerNorm over last dim (1024), f16 in, f32 out ----------
__global__ __launch_bounds__(256) void ln_f16(const _Float16* __restrict__ x,
                                              const float* __restrict__ g,
                                              const float* __restrict__ b,
                                              float* __restrict__ out) {
  const int row = blockIdx.x;
  const int t = threadIdx.x;
  const _Float16* xr = x + (size_t)row * FDIM;
  short4 raw = reinterpret_cast<const short4*>(xr)[t];
  union { short4 s; _Float16 h[4]; } u;
  u.s = raw;
  float v0 = (float)u.h[0], v1 = (float)u.h[1], v2 = (float)u.h[2], v3 = (float)u.h[3];
  float s = v0 + v1 + v2 + v3;
  float q = v0 * v0 + v1 * v1 + v2 * v2 + v3 * v3;
#pragma unroll
  for (int off = 32; off > 0; off >>= 1) {
    s += __shfl_down(s, off);
    q += __shfl_down(q, off);
  }
  __shared__ float ss[4], qs[4];
  int wave = t >> 6, lane = t & 63;
  if (lane == 0) { ss[wave] = s; qs[wave] = q; }
  __syncthreads();
  float S = ss[0] + ss[1] + ss[2] + ss[3];
  float Q = qs[0] + qs[1] + qs[2] + qs[3];
  float mu = S * (1.f / FDIM);
  float var = Q * (1.f / FDIM) - mu * mu;
  float rs = rsqrtf(var + 1e-5f);
  int c = t * 4;
  float4 o;
  o.x = (v0 - mu) * rs * g[c + 0] + b[c + 0];
  o.y = (v1 - mu) * rs * g[c + 1] + b[c + 1];
  o.z = (v2 - mu) * rs * g[c + 2] + b[c + 2];
  o.w = (v3 - mu) * rs * g[c + 3] + b[c + 3];
  reinterpret_cast<float4*>(out + (size_t)row * FDIM)[t] = o;
}

// ---------- launch ----------
extern "C" void kernel_launch(void* const* d_in, const int* in_sizes, int n_in,
                              void* d_out, int out_size, void* d_ws, size_t ws_size,
                              hipStream_t stream) {
  const float* spatial  = (const float*)d_in[0];
  const float* temporal = (const float*)d_in[1];
  const float* sp_w = (const float*)d_in[2];
  const float* sp_b = (const float*)d_in[3];
  const float* tp_w = (const float*)d_in[4];
  const float* tp_b = (const float*)d_in[5];
  const float* st_vw = (const float*)d_in[10];
  const float* st_vb = (const float*)d_in[11];
  const float* st_ow = (const float*)d_in[12];
  const float* st_ob = (const float*)d_in[13];
  const float* ts_vw = (const float*)d_in[18];
  const float* ts_vb = (const float*)d_in[19];
  const float* ts_ow = (const float*)d_in[20];
  const float* ts_ob = (const float*)d_in[21];
  const float* sa_vw = (const float*)d_in[26];
  const float* sa_vb = (const float*)d_in[27];
  const float* sa_ow = (const float*)d_in[28];
  const float* sa_ob = (const float*)d_in[29];
  const float* f1_w = (const float*)d_in[30];   // (1024, 2048)
  const float* f1_b = (const float*)d_in[31];
  const float* f2_w = (const float*)d_in[32];
  const float* f2_b = (const float*)d_in[33];
  const float* ln_g = (const float*)d_in[34];
  const float* ln_b = (const float*)d_in[35];

  // ---- workspace carve-up (bytes) ----
  char* base = (char*)d_ws;
  size_t off = 0;
  auto alloc = [&](size_t bytes) { void* p = base + off; off += (bytes + 255) & ~255ull; return p; };
  const size_t W16 = 1024 * 1024 * sizeof(_Float16);   // 2 MB

  _Float16* Xcat = (_Float16*)alloc((size_t)NB * 2048 * 2);  // 64 MB
  _Float16* h    = (_Float16*)alloc((size_t)NB * 1024 * 2);  // 32 MB
  _Float16* opre = (_Float16*)alloc((size_t)NB * 1024 * 2);  // 32 MB
  _Float16* st_owT = (_Float16*)alloc(W16);
  _Float16* st_vwT = (_Float16*)alloc(W16);
  _Float16* tp_wT  = (_Float16*)alloc(W16);
  _Float16* ts_owT = (_Float16*)alloc(W16);
  _Float16* ts_vwT = (_Float16*)alloc(W16);
  _Float16* sp_wT  = (_Float16*)alloc(W16);
  _Float16* sa_vwT = (_Float16*)alloc(W16);
  _Float16* f2_wT  = (_Float16*)alloc(W16);
  _Float16* f1a16  = (_Float16*)alloc(W16);
  _Float16* f1b16  = (_Float16*)alloc(W16);
  _Float16* sa_ow16= (_Float16*)alloc(W16);
  _Float16* T1t = (_Float16*)alloc(W16);
  _Float16* T1s = (_Float16*)alloc(W16);
  _Float16* T1a = (_Float16*)alloc(W16);
  _Float16* T2t = (_Float16*)alloc(W16);
  _Float16* T2s = (_Float16*)alloc(W16);
  _Float16* W2  = (_Float16*)alloc(W16);
  _Float16* Wh  = (_Float16*)alloc((size_t)1024 * 2048 * 2); // 4 MB
  float* u1 = (float*)alloc(3 * 1024 * 4);
  float* u2 = (float*)alloc(3 * 1024 * 4);
  float* bt = (float*)alloc(1024 * 4);
  float* bh = (float*)alloc(1024 * 4);
  // b2 = u2 + 2*1024

  // ---- 1) build Xcat = [temporal | spatial] in f16 ----
  cvt_strided<<<2048, 256, 0, stream>>>(temporal, 1024, Xcat, 2048, (long)NB * 256);
  cvt_strided<<<2048, 256, 0, stream>>>(spatial, 1024, Xcat + 1024, 2048, (long)NB * 256);

  // ---- 2) transposed f16 copies of right-hand weight operands ----
  TP8 tp;
  tp.in[0] = st_ow; tp.out[0] = st_owT;
  tp.in[1] = st_vw; tp.out[1] = st_vwT;
  tp.in[2] = tp_w;  tp.out[2] = tp_wT;
  tp.in[3] = ts_ow; tp.out[3] = ts_owT;
  tp.in[4] = ts_vw; tp.out[4] = ts_vwT;
  tp.in[5] = sp_w;  tp.out[5] = sp_wT;
  tp.in[6] = sa_vw; tp.out[6] = sa_vwT;
  tp.in[7] = f2_w;  tp.out[7] = f2_wT;
  transpose_cvt<<<dim3(32, 32, 8), 256, 0, stream>>>(tp);

  // ---- 3) f16 copies of left-hand operands ----
  cvt_strided<<<1024, 256, 0, stream>>>(f1_w, 2048, f1a16, 1024, 1024 * 256);
  cvt_strided<<<1024, 256, 0, stream>>>(f1_w + 1024, 2048, f1b16, 1024, 1024 * 256);
  cvt_strided<<<1024, 256, 0, stream>>>(sa_ow, 1024, sa_ow16, 1024, 1024 * 256);

  // ---- 4) bias chains (fp32 matvecs) ----
  {
    MV3 a;
    a.W[0] = st_vw; a.x[0] = tp_b; a.add[0] = st_vb; a.y[0] = u1;          a.ld[0] = 1024;
    a.W[1] = ts_vw; a.x[1] = sp_b; a.add[1] = ts_vb; a.y[1] = u1 + 1024;   a.ld[1] = 1024;
    a.W[2] = sa_vw; a.x[2] = f2_b; a.add[2] = sa_vb; a.y[2] = u1 + 2048;   a.ld[2] = 1024;
    matvec3<<<dim3(256, 3), 256, 0, stream>>>(a);
  }
  {
    MV3 a;
    a.W[0] = st_ow; a.x[0] = u1;        a.add[0] = st_ob; a.y[0] = u2;        a.ld[0] = 1024;
    a.W[1] = ts_ow; a.x[1] = u1 + 1024; a.add[1] = ts_ob; a.y[1] = u2 + 1024; a.ld[1] = 1024;
    a.W[2] = sa_ow; a.x[2] = u1 + 2048; a.add[2] = sa_ob; a.y[2] = u2 + 2048; a.ld[2] = 1024;
    matvec3<<<dim3(256, 3), 256, 0, stream>>>(a);
  }
  {
    MV3 a;  // bt = f1a@u2_s + f1_b
    a.W[0] = f1_w; a.x[0] = u2; a.add[0] = f1_b; a.y[0] = bt; a.ld[0] = 2048;
    matvec3<<<dim3(256, 1), 256, 0, stream>>>(a);
  }
  {
    MV3 a;  // bh = f1b@u2_t + bt
    a.W[0] = f1_w + 1024; a.x[0] = u2 + 1024; a.add[0] = bt; a.y[0] = bh; a.ld[0] = 2048;
    matvec3<<<dim3(256, 1), 256, 0, stream>>>(a);
  }

  // ---- 5) weight-combine GEMMs (f16, f32-accum), 3 batched stages ----
  auto wgemm = [&](GB3& g, int nb, int M, int N, int K) {
    dim3 grid((M / 128) * (N / 128), nb);
    gemm_f16<0><<<grid, 256, 0, stream>>>(g, M, N, K);
  };
  {
    GB3 g = {};
    g.g[0] = { f1a16,  st_owT, nullptr, T1t, 1024 };
    g.g[1] = { f1b16,  ts_owT, nullptr, T1s, 1024 };
    g.g[2] = { sa_ow16, sa_vwT, nullptr, T1a, 1024 };
    wgemm(g, 3, 1024, 1024, 1024);
  }
  {
    GB3 g = {};
    g.g[0] = { T1t, st_vwT, nullptr, T2t, 1024 };
    g.g[1] = { T1s, ts_vwT, nullptr, T2s, 1024 };
    g.g[2] = { T1a, f2_wT,  nullptr, W2,  1024 };
    wgemm(g, 3, 1024, 1024, 1024);
  }
  {
    GB3 g = {};
    g.g[0] = { T2t, tp_wT, nullptr, Wh,        2048 };
    g.g[1] = { T2s, sp_wT, nullptr, Wh + 1024, 2048 };
    wgemm(g, 2, 1024, 1024, 1024);
  }

  // ---- 6) the two surviving big GEMMs ----
  {
    GB3 g = {};
    g.g[0] = { Xcat, Wh, bh, h, 1024 };
    dim3 grid((NB / 128) * (1024 / 128), 1);
    gemm_f16<1><<<grid, 256, 0, stream>>>(g, NB, 1024, 2048);
  }
  {
    GB3 g = {};
    g.g[0] = { h, W2, u2 + 2048, opre, 1024 };
    dim3 grid((NB / 128) * (1024 / 128), 1);
    gemm_f16<0><<<grid, 256, 0, stream>>>(g, NB, 1024, 1024);
  }

  // ---- 7) LayerNorm ----
  ln_f16<<<NB, 256, 0, stream>>>(opre, ln_g, ln_b, (float*)d_out);
}

// Round 3
// 247.581 us; speedup vs baseline: 2.1681x; 1.1589x over previous
//
#include <hip/hip_runtime.h>
#include <hip/hip_fp16.h>

// SpatioTemporalFusion — folded to 2 big GEMMs + weight-combine tree + LN.
//   h    = relu(Xcat @ Wh^T + bh),  Xcat=[temporal|spatial] (16384x2048)
//   out  = LN(h @ W2^T + b2)
// Wh_t = (f1a@st_ow)@(st_vw@tp_w), Wh_s = (f1b@ts_ow)@(ts_vw@sp_w),
// W2   = (sa_ow@sa_vw)@f2_w   — 2-level tree, batched.
// Big GEMMs: 256x256 tile, BK=64, 8 waves, 8-phase schedule with counted
// vmcnt(6), LDS XOR-swizzle (read-side) + pre-swizzled global source,
// inline-asm ds_read_b128 + lgkmcnt(0) + sched_barrier(0), setprio around MFMA.

typedef _Float16 half8 __attribute__((ext_vector_type(8)));
typedef float floatx4 __attribute__((ext_vector_type(4)));

#define GLOBAL_AS __attribute__((address_space(1)))
#define LDS_AS __attribute__((address_space(3)))

#define NB 16384
#define FDIM 1024

#define SBAR() asm volatile("s_barrier" ::: "memory")
#define WAIT_LGKM0() asm volatile("s_waitcnt lgkmcnt(0)" ::: "memory")
#define WAIT_VM(n) asm volatile("s_waitcnt vmcnt(" #n ")" ::: "memory")
#define DSREAD(dst, addr) asm volatile("ds_read_b128 %0, %1" : "=v"(dst) : "v"(addr))

// ---------------- 256^2 8-phase GEMM: C = A@W^T + bias (opt relu) ----------------
template <int RELU>
__global__ __launch_bounds__(512, 2) void gemm256(
    const _Float16* __restrict__ A, const _Float16* __restrict__ W,
    const float* __restrict__ bias, _Float16* __restrict__ C,
    int M, int N, int K, int ldc) {
  __shared__ __align__(16) _Float16 smem[2 * 2 * 256 * 64];  // 128 KiB

  const int t = threadIdx.x;
  const int lane = t & 63;
  const int w = t >> 6;        // wave 0..7
  const int wr = w >> 2;       // 0..1 -> 128-row slab
  const int wc = w & 3;        // 0..3 -> 64-col slab

  const int nwg = gridDim.x;
  const int bid = blockIdx.x;
  const int swz = (bid & 7) * (nwg >> 3) + (bid >> 3);
  const int nTN = N >> 8;
  const int m0 = (swz / nTN) << 8;
  const int n0 = (swz % nTN) << 8;
  const int NT = K >> 6;       // number of BK=64 K-tiles

  // ---- staging: per-thread pre-swizzled global source ----
  // half-tile = 128 rows x 64 cols (16 KiB). slot = w*128 + j*64 + lane.
  // row = w*16 + j*8 + (lane>>3), cs = lane&7; source col-slot = cs ^ (row&7).
  const int srow = w * 16 + (lane >> 3);
  const int scs = (lane & 7) ^ ((lane >> 3) & 7);
  const char* gA = (const char*)(A + (long)(m0 + srow) * K + scs * 8);
  const char* gB = (const char*)(W + (long)(n0 + srow) * K + scs * 8);
  const long dJ = (long)K * 16;    // +8 rows (issue 1)
  const long dH = (long)K * 256;   // +128 rows (half 1)
  const int ldst = w * 2048 + lane * 16;

  // ---- fragment reads: swizzled LDS byte addresses ----
  unsigned sb = (unsigned)(unsigned long long)(LDS_AS void*)smem;
  const int frow = lane & 15;
  const unsigned offk = (unsigned)((((lane >> 4) * 16) ^ ((frow & 7) << 4)));
  const unsigned aoff = (unsigned)((wr * 128 + frow) * 128);
  const unsigned boff = (unsigned)(32768 + (wc * 64 + frow) * 128);

  floatx4 acc[8][4] = {};

#define STAGE(ab, h, buf, gp, kb)                                               \
  do {                                                                          \
    const char* _s = (gp) + (h) * dH + (kb);                                    \
    char* _d = (char*)smem + (buf) * 65536 + (ab) * 32768 + (h) * 16384 + ldst; \
    __builtin_amdgcn_global_load_lds((const GLOBAL_AS void*)_s,                 \
                                     (LDS_AS void*)_d, 16, 0, 0);               \
    __builtin_amdgcn_global_load_lds((const GLOBAL_AS void*)(_s + dJ),          \
                                     (LDS_AS void*)(_d + 1024), 16, 0, 0);      \
  } while (0)

#define QUAD(a0, a1, i0, i1)                                                              \
  do {                                                                                    \
    __builtin_amdgcn_s_setprio(1);                                                       \
    _Pragma("unroll") for (int c = 0; c < 4; ++c) {                                      \
      acc[i0][c] = __builtin_amdgcn_mfma_f32_16x16x32_f16(a0[0], b[c][0], acc[i0][c], 0, 0, 0); \
      acc[i0][c] = __builtin_amdgcn_mfma_f32_16x16x32_f16(a0[1], b[c][1], acc[i0][c], 0, 0, 0); \
      acc[i1][c] = __builtin_amdgcn_mfma_f32_16x16x32_f16(a1[0], b[c][0], acc[i1][c], 0, 0, 0); \
      acc[i1][c] = __builtin_amdgcn_mfma_f32_16x16x32_f16(a1[1], b[c][1], acc[i1][c], 0, 0, 0); \
    }                                                                                     \
    __builtin_amdgcn_s_setprio(0);                                                       \
  } while (0)

  // prologue: tile0 {A0,A1,B0,B1}, tile1 {B0,A0,A1}; vmcnt(6) => tile0 resident
  {
    const long k1 = (NT > 1 ? 1 : 0) * 128L;
    STAGE(0, 0, 0, gA, 0); STAGE(0, 1, 0, gA, 0);
    STAGE(1, 0, 0, gB, 0); STAGE(1, 1, 0, gB, 0);
    STAGE(1, 0, 1, gB, k1); STAGE(0, 0, 1, gA, k1); STAGE(0, 1, 1, gA, k1);
  }
  WAIT_VM(6);
  SBAR();

  for (int kt = 0; kt < NT; ++kt) {
    const int cur = kt & 1, nxt = cur ^ 1;
    const unsigned baseA = sb + (unsigned)(cur * 65536) + aoff;
    const unsigned baseB = sb + (unsigned)(cur * 65536) + boff;
    const long kb1 = (long)(kt + 1 < NT ? kt + 1 : NT - 1) * 128;
    const long kb2 = (long)(kt + 2 < NT ? kt + 2 : NT - 1) * 128;

    half8 b[4][2], alo[4][2], ahi[4][2];

    // phase 1: read all B + A rows 0-3; prefetch (t+1):B1 -> nxt buf
#pragma unroll
    for (int c = 0; c < 4; ++c) {
      DSREAD(b[c][0], baseB + c * 2048 + offk);
      DSREAD(b[c][1], baseB + c * 2048 + (offk ^ 64u));
    }
#pragma unroll
    for (int r = 0; r < 4; ++r) {
      DSREAD(alo[r][0], baseA + r * 2048 + offk);
      DSREAD(alo[r][1], baseA + r * 2048 + (offk ^ 64u));
    }
    STAGE(1, 1, nxt, gB, kb1);
    SBAR();
    WAIT_LGKM0();
    __builtin_amdgcn_sched_barrier(0);
    QUAD(alo[0], alo[1], 0, 1);
    SBAR();

    // phase 2: read A rows 4-7; prefetch (t+2):B0 -> cur buf (B dead after ph1)
#pragma unroll
    for (int r = 0; r < 4; ++r) {
      DSREAD(ahi[r][0], baseA + (r + 4) * 2048 + offk);
      DSREAD(ahi[r][1], baseA + (r + 4) * 2048 + (offk ^ 64u));
    }
    STAGE(1, 0, cur, gB, kb2);
    SBAR();
    WAIT_LGKM0();           // ahi complete before ph3's A0 staging (all waves by barrier)
    __builtin_amdgcn_sched_barrier(0);
    QUAD(alo[2], alo[3], 2, 3);
    SBAR();

    // phase 3: prefetch (t+2):A0 -> cur (A reads all complete)
    STAGE(0, 0, cur, gA, kb2);
    SBAR();
    __builtin_amdgcn_sched_barrier(0);
    QUAD(ahi[0], ahi[1], 4, 5);
    SBAR();

    // phase 4: prefetch (t+2):A1; boundary vmcnt(6) => tile t+1 fully resident
    STAGE(0, 1, cur, gA, kb2);
    WAIT_VM(6);
    SBAR();
    __builtin_amdgcn_sched_barrier(0);
    QUAD(ahi[2], ahi[3], 6, 7);
    SBAR();
  }
  WAIT_VM(0);  // drain tail garbage loads before LDS dealloc

  // epilogue: C/D layout col = lane&15, row = (lane>>4)*4 + j
  const int rbase = (lane >> 4) * 4;
#pragma unroll
  for (int c = 0; c < 4; ++c) {
    const int col = n0 + wc * 64 + c * 16 + frow;
    const float bv = bias[col];
#pragma unroll
    for (int r = 0; r < 8; ++r) {
#pragma unroll
      for (int j = 0; j < 4; ++j) {
        int row = m0 + wr * 128 + r * 16 + rbase + j;
        float v = acc[r][c][j] + bv;
        if (RELU) v = fmaxf(v, 0.f);
        C[(long)row * ldc + col] = (_Float16)v;
      }
    }
  }
#undef STAGE
#undef QUAD
}

// ---------------- strided f32 -> f16 convert (1024 cols = 256 float4/row) ----------------
__global__ __launch_bounds__(256) void cvt_strided(const float* __restrict__ in, long ld_in,
                                                   _Float16* __restrict__ out, long ld_out,
                                                   long n4) {
  long i = (long)blockIdx.x * blockDim.x + threadIdx.x;
  long stride = (long)gridDim.x * blockDim.x;
  for (; i < n4; i += stride) {
    long row = i >> 8;
    long c4 = i & 255;
    float4 v = *reinterpret_cast<const float4*>(in + row * ld_in + c4 * 4);
    union { _Float16 h[4]; short4 s; } u;
    u.h[0] = (_Float16)v.x; u.h[1] = (_Float16)v.y;
    u.h[2] = (_Float16)v.z; u.h[3] = (_Float16)v.w;
    *reinterpret_cast<short4*>(out + row * ld_out + c4 * 4) = u.s;
  }
}

// ---------------- batched 1024x1024 transpose + f32->f16 ----------------
struct TP8 { const float* in[8]; _Float16* out[8]; };
__global__ __launch_bounds__(256) void transpose_cvt(TP8 args) {
  __shared__ float tile[32][33];
  const float* in = args.in[blockIdx.z];
  _Float16* out = args.out[blockIdx.z];
  const int bx = blockIdx.x * 32;
  const int by = blockIdx.y * 32;
  const int tx = threadIdx.x & 31;
  const int ty = threadIdx.x >> 5;
#pragma unroll
  for (int r = 0; r < 32; r += 8)
    tile[ty + r][tx] = in[(long)(by + ty + r) * 1024 + bx + tx];
  __syncthreads();
#pragma unroll
  for (int r = 0; r < 32; r += 8)
    out[(long)(bx + ty + r) * 1024 + by + tx] = (_Float16)tile[tx][ty + r];
}

// ---------------- batched matvec: y = W@x + add ----------------
struct MV3 {
  const float* W[3]; const float* x[3]; const float* add[3]; float* y[3]; long ld[3];
};
__global__ __launch_bounds__(256) void matvec3(MV3 a) {
  const int b = blockIdx.y;
  const int row = blockIdx.x * 4 + (threadIdx.x >> 6);
  const int lane = threadIdx.x & 63;
  const float* wr = a.W[b] + (long)row * a.ld[b];
  const float* xv = a.x[b];
  float s = 0.f;
#pragma unroll
  for (int j = 0; j < 4; ++j) {
    float4 w4 = *reinterpret_cast<const float4*>(wr + (lane + 64 * j) * 4);
    float4 x4 = *reinterpret_cast<const float4*>(xv + (lane + 64 * j) * 4);
    s += w4.x * x4.x + w4.y * x4.y + w4.z * x4.z + w4.w * x4.w;
  }
#pragma unroll
  for (int off = 32; off > 0; off >>= 1) s += __shfl_down(s, off);
  if (lane == 0) {
    const float* ad = a.add[b];
    a.y[b][row] = s + (ad ? ad[row] : 0.f);
  }
}

// ---------------- 128^2 GEMM (weight-combine), batched over blockIdx.y ----------------
struct GemmArgs { const _Float16* A; const _Float16* W; const float* bias; _Float16* C; int ldc; };
struct GB5 { GemmArgs g[5]; };

__global__ __launch_bounds__(256, 2) void gemm_f16(GB5 args, int M, int N, int K) {
  __shared__ __align__(16) _Float16 As[128 * 32];
  __shared__ __align__(16) _Float16 Ws[128 * 32];

  const GemmArgs ga = args.g[blockIdx.y];
  const int t = threadIdx.x;
  const int lane = t & 63;
  const int wave = t >> 6;
  const int wr = wave >> 1;
  const int wc = wave & 1;

  const int nwg = gridDim.x;
  const int bid = blockIdx.x;
  const int swz = (bid & 7) * (nwg >> 3) + (bid >> 3);
  const int nTilesN = N >> 7;
  const int m0 = (swz / nTilesN) << 7;
  const int n0 = (swz % nTilesN) << 7;

  floatx4 acc[4][4] = {};
  const int srow = t >> 2;
  const int scol = (t & 3) * 8;
  const _Float16* Ag = ga.A + (long)(m0 + srow) * K + scol;
  const _Float16* Wg = ga.W + (long)(n0 + srow) * K + scol;
  const int frow = lane & 15;
  const int fk = (lane >> 4) * 8;

  for (int k0 = 0; k0 < K; k0 += 32) {
#pragma unroll
    for (int i = 0; i < 2; ++i) {
      __builtin_amdgcn_global_load_lds(
          (const GLOBAL_AS void*)(Ag + (long)i * 64 * K + k0),
          (LDS_AS void*)(&As[i * 2048 + t * 8]), 16, 0, 0);
      __builtin_amdgcn_global_load_lds(
          (const GLOBAL_AS void*)(Wg + (long)i * 64 * K + k0),
          (LDS_AS void*)(&Ws[i * 2048 + t * 8]), 16, 0, 0);
    }
    __syncthreads();
    half8 a[4], b[4];
#pragma unroll
    for (int r = 0; r < 4; ++r)
      a[r] = *(const half8*)&As[(wr * 64 + r * 16 + frow) * 32 + fk];
#pragma unroll
    for (int c = 0; c < 4; ++c)
      b[c] = *(const half8*)&Ws[(wc * 64 + c * 16 + frow) * 32 + fk];
#pragma unroll
    for (int r = 0; r < 4; ++r)
#pragma unroll
      for (int c = 0; c < 4; ++c)
        acc[r][c] = __builtin_amdgcn_mfma_f32_16x16x32_f16(a[r], b[c], acc[r][c], 0, 0, 0);
    __syncthreads();
  }

  const int rbase = lane >> 4;
#pragma unroll
  for (int c = 0; c < 4; ++c) {
    const int col = n0 + wc * 64 + c * 16 + frow;
    const float bv = ga.bias ? ga.bias[col] : 0.f;
#pragma unroll
    for (int r = 0; r < 4; ++r)
#pragma unroll
      for (int j = 0; j < 4; ++j) {
        int row = m0 + wr * 64 + r * 16 + rbase * 4 + j;
        ga.C[(long)row * ga.ldc + col] = (_Float16)(acc[r][c][j] + bv);
      }
  }
}

// ---------------- LayerNorm (1024), f16 in, f32 out ----------------
__global__ __launch_bounds__(256) void ln_f16(const _Float16* __restrict__ x,
                                              const float* __restrict__ g,
                                              const float* __restrict__ b,
                                              float* __restrict__ out) {
  const int row = blockIdx.x;
  const int t = threadIdx.x;
  const _Float16* xr = x + (size_t)row * FDIM;
  short4 raw = reinterpret_cast<const short4*>(xr)[t];
  union { short4 s; _Float16 h[4]; } u;
  u.s = raw;
  float v0 = (float)u.h[0], v1 = (float)u.h[1], v2 = (float)u.h[2], v3 = (float)u.h[3];
  float s = v0 + v1 + v2 + v3;
  float q = v0 * v0 + v1 * v1 + v2 * v2 + v3 * v3;
#pragma unroll
  for (int off = 32; off > 0; off >>= 1) {
    s += __shfl_down(s, off);
    q += __shfl_down(q, off);
  }
  __shared__ float ss[4], qs[4];
  int wave = t >> 6, lane = t & 63;
  if (lane == 0) { ss[wave] = s; qs[wave] = q; }
  __syncthreads();
  float S = ss[0] + ss[1] + ss[2] + ss[3];
  float Q = qs[0] + qs[1] + qs[2] + qs[3];
  float mu = S * (1.f / FDIM);
  float var = Q * (1.f / FDIM) - mu * mu;
  float rs = rsqrtf(var + 1e-5f);
  int c = t * 4;
  float4 o;
  o.x = (v0 - mu) * rs * g[c + 0] + b[c + 0];
  o.y = (v1 - mu) * rs * g[c + 1] + b[c + 1];
  o.z = (v2 - mu) * rs * g[c + 2] + b[c + 2];
  o.w = (v3 - mu) * rs * g[c + 3] + b[c + 3];
  reinterpret_cast<float4*>(out + (size_t)row * FDIM)[t] = o;
}

// ---------------- launch ----------------
extern "C" void kernel_launch(void* const* d_in, const int* in_sizes, int n_in,
                              void* d_out, int out_size, void* d_ws, size_t ws_size,
                              hipStream_t stream) {
  const float* spatial  = (const float*)d_in[0];
  const float* temporal = (const float*)d_in[1];
  const float* sp_w = (const float*)d_in[2];
  const float* sp_b = (const float*)d_in[3];
  const float* tp_w = (const float*)d_in[4];
  const float* tp_b = (const float*)d_in[5];
  const float* st_vw = (const float*)d_in[10];
  const float* st_vb = (const float*)d_in[11];
  const float* st_ow = (const float*)d_in[12];
  const float* st_ob = (const float*)d_in[13];
  const float* ts_vw = (const float*)d_in[18];
  const float* ts_vb = (const float*)d_in[19];
  const float* ts_ow = (const float*)d_in[20];
  const float* ts_ob = (const float*)d_in[21];
  const float* sa_vw = (const float*)d_in[26];
  const float* sa_vb = (const float*)d_in[27];
  const float* sa_ow = (const float*)d_in[28];
  const float* sa_ob = (const float*)d_in[29];
  const float* f1_w = (const float*)d_in[30];   // (1024, 2048)
  const float* f1_b = (const float*)d_in[31];
  const float* f2_w = (const float*)d_in[32];
  const float* f2_b = (const float*)d_in[33];
  const float* ln_g = (const float*)d_in[34];
  const float* ln_b = (const float*)d_in[35];

  char* base = (char*)d_ws;
  size_t off = 0;
  auto alloc = [&](size_t bytes) { void* p = base + off; off += (bytes + 255) & ~255ull; return p; };
  const size_t W16 = 1024 * 1024 * sizeof(_Float16);

  _Float16* Xcat = (_Float16*)alloc((size_t)NB * 2048 * 2);
  _Float16* h    = (_Float16*)alloc((size_t)NB * 1024 * 2);
  _Float16* opre = (_Float16*)alloc((size_t)NB * 1024 * 2);
  _Float16* st_owT = (_Float16*)alloc(W16);
  _Float16* ts_owT = (_Float16*)alloc(W16);
  _Float16* sa_vwT = (_Float16*)alloc(W16);
  _Float16* tp_wT  = (_Float16*)alloc(W16);
  _Float16* sp_wT  = (_Float16*)alloc(W16);
  _Float16* f2_wT  = (_Float16*)alloc(W16);
  _Float16* f1a16  = (_Float16*)alloc(W16);
  _Float16* f1b16  = (_Float16*)alloc(W16);
  _Float16* sa_ow16= (_Float16*)alloc(W16);
  _Float16* st_vw16= (_Float16*)alloc(W16);
  _Float16* ts_vw16= (_Float16*)alloc(W16);
  _Float16* P1 = (_Float16*)alloc(W16);
  _Float16* Q2 = (_Float16*)alloc(W16);
  _Float16* P3 = (_Float16*)alloc(W16);
  _Float16* Q4 = (_Float16*)alloc(W16);
  _Float16* P5 = (_Float16*)alloc(W16);
  _Float16* W2 = (_Float16*)alloc(W16);
  _Float16* Wh = (_Float16*)alloc((size_t)1024 * 2048 * 2);
  float* u1 = (float*)alloc(3 * 1024 * 4);
  float* u2 = (float*)alloc(3 * 1024 * 4);
  float* bt = (float*)alloc(1024 * 4);
  float* bh = (float*)alloc(1024 * 4);

  // 1) Xcat = [temporal | spatial] f16
  cvt_strided<<<2048, 256, 0, stream>>>(temporal, 1024, Xcat, 2048, (long)NB * 256);
  cvt_strided<<<2048, 256, 0, stream>>>(spatial, 1024, Xcat + 1024, 2048, (long)NB * 256);

  // 2) transposed f16 weights
  TP8 tp = {};
  tp.in[0] = st_ow; tp.out[0] = st_owT;
  tp.in[1] = ts_ow; tp.out[1] = ts_owT;
  tp.in[2] = sa_vw; tp.out[2] = sa_vwT;
  tp.in[3] = tp_w;  tp.out[3] = tp_wT;
  tp.in[4] = sp_w;  tp.out[4] = sp_wT;
  tp.in[5] = f2_w;  tp.out[5] = f2_wT;
  transpose_cvt<<<dim3(32, 32, 6), 256, 0, stream>>>(tp);

  // 3) plain f16 weights
  cvt_strided<<<1024, 256, 0, stream>>>(f1_w, 2048, f1a16, 1024, 1024 * 256);
  cvt_strided<<<1024, 256, 0, stream>>>(f1_w + 1024, 2048, f1b16, 1024, 1024 * 256);
  cvt_strided<<<1024, 256, 0, stream>>>(sa_ow, 1024, sa_ow16, 1024, 1024 * 256);
  cvt_strided<<<1024, 256, 0, stream>>>(st_vw, 1024, st_vw16, 1024, 1024 * 256);
  cvt_strided<<<1024, 256, 0, stream>>>(ts_vw, 1024, ts_vw16, 1024, 1024 * 256);

  // 4) bias chains (fp32 matvecs)
  {
    MV3 a;
    a.W[0] = st_vw; a.x[0] = tp_b; a.add[0] = st_vb; a.y[0] = u1;        a.ld[0] = 1024;
    a.W[1] = ts_vw; a.x[1] = sp_b; a.add[1] = ts_vb; a.y[1] = u1 + 1024; a.ld[1] = 1024;
    a.W[2] = sa_vw; a.x[2] = f2_b; a.add[2] = sa_vb; a.y[2] = u1 + 2048; a.ld[2] = 1024;
    matvec3<<<dim3(256, 3), 256, 0, stream>>>(a);
  }
  {
    MV3 a;
    a.W[0] = st_ow; a.x[0] = u1;        a.add[0] = st_ob; a.y[0] = u2;        a.ld[0] = 1024;
    a.W[1] = ts_ow; a.x[1] = u1 + 1024; a.add[1] = ts_ob; a.y[1] = u2 + 1024; a.ld[1] = 1024;
    a.W[2] = sa_ow; a.x[2] = u1 + 2048; a.add[2] = sa_ob; a.y[2] = u2 + 2048; a.ld[2] = 1024;
    matvec3<<<dim3(256, 3), 256, 0, stream>>>(a);
  }
  {
    MV3 a;
    a.W[0] = f1_w; a.x[0] = u2; a.add[0] = f1_b; a.y[0] = bt; a.ld[0] = 2048;
    matvec3<<<dim3(256, 1), 256, 0, stream>>>(a);
  }
  {
    MV3 a;
    a.W[0] = f1_w + 1024; a.x[0] = u2 + 1024; a.add[0] = bt; a.y[0] = bh; a.ld[0] = 2048;
    matvec3<<<dim3(256, 1), 256, 0, stream>>>(a);
  }

  // 5) weight tree — stage A: P1=f1a@st_ow, Q2=(st_vw@tp_w)^T, P3=f1b@ts_ow,
  //    Q4=(ts_vw@sp_w)^T, P5=sa_ow@sa_vw   (5 batched 1024^3)
  {
    GB5 g = {};
    g.g[0] = { f1a16,  st_owT, nullptr, P1, 1024 };
    g.g[1] = { tp_wT,  st_vw16, nullptr, Q2, 1024 };
    g.g[2] = { f1b16,  ts_owT, nullptr, P3, 1024 };
    g.g[3] = { sp_wT,  ts_vw16, nullptr, Q4, 1024 };
    g.g[4] = { sa_ow16, sa_vwT, nullptr, P5, 1024 };
    gemm_f16<<<dim3(64, 5), 256, 0, stream>>>(g, 1024, 1024, 1024);
  }
  // stage B: Wh_t = P1@Q2^T, Wh_s = P3@Q4^T, W2 = P5@f2_w
  {
    GB5 g = {};
    g.g[0] = { P1, Q2, nullptr, Wh,        2048 };
    g.g[1] = { P3, Q4, nullptr, Wh + 1024, 2048 };
    g.g[2] = { P5, f2_wT, nullptr, W2,     1024 };
    gemm_f16<<<dim3(64, 3), 256, 0, stream>>>(g, 1024, 1024, 1024);
  }

  // 6) big GEMMs (256^2 8-phase)
  gemm256<1><<<dim3(256), 512, 0, stream>>>(Xcat, Wh, bh, h, NB, 1024, 2048, 1024);
  gemm256<0><<<dim3(256), 512, 0, stream>>>(h, W2, u2 + 2048, opre, NB, 1024, 1024, 1024);

  // 7) LayerNorm
  ln_f16<<<NB, 256, 0, stream>>>(opre, ln_g, ln_b, (float*)d_out);
}

// Round 4
// 234.055 us; speedup vs baseline: 2.2934x; 1.0578x over previous
//
#include <hip/hip_runtime.h>
#include <hip/hip_fp16.h>

// SpatioTemporalFusion — folded to 2 big GEMMs + weight-combine tree + LN.
//   h    = relu(Xcat @ Wh^T + bh),  Xcat=[temporal|spatial] (16384x2048)
//   out  = LN(h @ W2^T + b2)
// gemm256: 256x256 tile, BK=64, 8 waves, 4-phase schedule, balanced ds_reads
// (12/4/4/4), STAGE ring {ph1:A0(t+1)->nxt, ph2:A1(t+1)->nxt,
// ph3:B0(t+2)->cur, ph4:B1(t+2)->cur}, counted vmcnt(4), read-side
// XOR-swizzle + pre-swizzled global source, setprio around MFMA.

typedef _Float16 half8 __attribute__((ext_vector_type(8)));
typedef float floatx4 __attribute__((ext_vector_type(4)));

#define GLOBAL_AS __attribute__((address_space(1)))
#define LDS_AS __attribute__((address_space(3)))

#define NB 16384
#define FDIM 1024

#define SBAR() asm volatile("s_barrier" ::: "memory")
#define WAIT_LGKM0() asm volatile("s_waitcnt lgkmcnt(0)" ::: "memory")
#define WAIT_VM(n) asm volatile("s_waitcnt vmcnt(" #n ")" ::: "memory")
#define DSREAD(dst, addr) asm volatile("ds_read_b128 %0, %1" : "=v"(dst) : "v"(addr))

// ---------------- 256^2 4-phase GEMM: C = A@W^T + bias (opt relu) ----------------
template <int RELU>
__global__ __launch_bounds__(512, 2) void gemm256(
    const _Float16* __restrict__ A, const _Float16* __restrict__ W,
    const float* __restrict__ bias, _Float16* __restrict__ C,
    int M, int N, int K, int ldc) {
  __shared__ __align__(16) _Float16 smem[2 * 2 * 256 * 64];  // 128 KiB

  const int t = threadIdx.x;
  const int lane = t & 63;
  const int w = t >> 6;        // wave 0..7
  const int wr = w >> 2;       // 0..1 -> 128-row slab
  const int wc = w & 3;        // 0..3 -> 64-col slab

  const int nwg = gridDim.x;
  const int bid = blockIdx.x;
  const int swz = (bid & 7) * (nwg >> 3) + (bid >> 3);
  const int nTN = N >> 8;
  const int m0 = (swz / nTN) << 8;
  const int n0 = (swz % nTN) << 8;
  const int NT = K >> 6;       // number of BK=64 K-tiles (>=2 here)

  // staging: half-tile = 128 rows x 64 cols (16 KiB); pre-swizzled global source
  const int srow = w * 16 + (lane >> 3);
  const int scs = (lane & 7) ^ ((lane >> 3) & 7);
  const char* gA = (const char*)(A + (long)(m0 + srow) * K + scs * 8);
  const char* gB = (const char*)(W + (long)(n0 + srow) * K + scs * 8);
  const long dJ = (long)K * 16;    // +8 rows
  const long dH = (long)K * 256;   // +128 rows
  const int ldst = w * 2048 + lane * 16;

  // fragment reads: swizzled LDS byte addresses
  unsigned sb = (unsigned)(unsigned long long)(LDS_AS void*)smem;
  const int frow = lane & 15;
  const unsigned offk = (unsigned)((((lane >> 4) * 16) ^ ((frow & 7) << 4)));
  const unsigned aoff = (unsigned)((wr * 128 + frow) * 128);
  const unsigned boff = (unsigned)(32768 + (wc * 64 + frow) * 128);

  floatx4 acc[8][4] = {};

#define STAGE(ab, hf, buf, gp, kb)                                               \
  do {                                                                           \
    const char* _s = (gp) + (hf) * dH + (kb);                                    \
    char* _d = (char*)smem + (buf) * 65536 + (ab) * 32768 + (hf) * 16384 + ldst; \
    __builtin_amdgcn_global_load_lds((const GLOBAL_AS void*)_s,                  \
                                     (LDS_AS void*)_d, 16, 0, 0);                \
    __builtin_amdgcn_global_load_lds((const GLOBAL_AS void*)(_s + dJ),           \
                                     (LDS_AS void*)(_d + 1024), 16, 0, 0);       \
  } while (0)

#define QUAD(a0, a1, i0, i1)                                                              \
  do {                                                                                    \
    __builtin_amdgcn_s_setprio(1);                                                       \
    _Pragma("unroll") for (int c = 0; c < 4; ++c) {                                      \
      acc[i0][c] = __builtin_amdgcn_mfma_f32_16x16x32_f16(a0[0], b[c][0], acc[i0][c], 0, 0, 0); \
      acc[i0][c] = __builtin_amdgcn_mfma_f32_16x16x32_f16(a0[1], b[c][1], acc[i0][c], 0, 0, 0); \
      acc[i1][c] = __builtin_amdgcn_mfma_f32_16x16x32_f16(a1[0], b[c][0], acc[i1][c], 0, 0, 0); \
      acc[i1][c] = __builtin_amdgcn_mfma_f32_16x16x32_f16(a1[1], b[c][1], acc[i1][c], 0, 0, 0); \
    }                                                                                     \
    __builtin_amdgcn_s_setprio(0);                                                       \
  } while (0)

  // prologue: tile0 {A0,A1,B0,B1}->buf0, tile1 {B0,B1}->buf1; vmcnt(4) => tile0 resident
  {
    const long k1 = 128L;  // NT >= 2
    STAGE(0, 0, 0, gA, 0); STAGE(0, 1, 0, gA, 0);
    STAGE(1, 0, 0, gB, 0); STAGE(1, 1, 0, gB, 0);
    STAGE(1, 0, 1, gB, k1); STAGE(1, 1, 1, gB, k1);
  }
  WAIT_VM(4);
  SBAR();

  for (int kt = 0; kt < NT; ++kt) {
    const int cur = kt & 1, nxt = cur ^ 1;
    const unsigned baseA = sb + (unsigned)(cur * 65536) + aoff;
    const unsigned baseB = sb + (unsigned)(cur * 65536) + boff;
    const long kb1 = (long)(kt + 1 < NT ? kt + 1 : NT - 1) * 128;
    const long kb2 = (long)(kt + 2 < NT ? kt + 2 : NT - 1) * 128;

    half8 b[4][2], alo[4][2], ahi[4][2];

    // ph1: read B (8) + A rows 0-1 (4); stage A0(t+1)->nxt (A-nxt dead since t-1)
#pragma unroll
    for (int c = 0; c < 4; ++c) {
      DSREAD(b[c][0], baseB + c * 2048 + offk);
      DSREAD(b[c][1], baseB + c * 2048 + (offk ^ 64u));
    }
#pragma unroll
    for (int r = 0; r < 2; ++r) {
      DSREAD(alo[r][0], baseA + r * 2048 + offk);
      DSREAD(alo[r][1], baseA + r * 2048 + (offk ^ 64u));
    }
    STAGE(0, 0, nxt, gA, kb1);
    SBAR();
    WAIT_LGKM0();
    __builtin_amdgcn_sched_barrier(0);
    QUAD(alo[0], alo[1], 0, 1);
    SBAR();

    // ph2: read A rows 2-3 (4); stage A1(t+1)->nxt
#pragma unroll
    for (int r = 2; r < 4; ++r) {
      DSREAD(alo[r][0], baseA + r * 2048 + offk);
      DSREAD(alo[r][1], baseA + r * 2048 + (offk ^ 64u));
    }
    STAGE(0, 1, nxt, gA, kb1);
    SBAR();
    WAIT_LGKM0();
    __builtin_amdgcn_sched_barrier(0);
    QUAD(alo[2], alo[3], 2, 3);
    SBAR();

    // ph3: read A rows 4-5 (4); stage B0(t+2)->cur (B-cur dead since ph1)
#pragma unroll
    for (int r = 0; r < 2; ++r) {
      DSREAD(ahi[r][0], baseA + (r + 4) * 2048 + offk);
      DSREAD(ahi[r][1], baseA + (r + 4) * 2048 + (offk ^ 64u));
    }
    STAGE(1, 0, cur, gB, kb2);
    SBAR();
    WAIT_LGKM0();
    __builtin_amdgcn_sched_barrier(0);
    QUAD(ahi[0], ahi[1], 4, 5);
    SBAR();

    // ph4: read A rows 6-7 (4); stage B1(t+2)->cur; vmcnt(4) => tile t+1 resident
#pragma unroll
    for (int r = 2; r < 4; ++r) {
      DSREAD(ahi[r][0], baseA + (r + 4) * 2048 + offk);
      DSREAD(ahi[r][1], baseA + (r + 4) * 2048 + (offk ^ 64u));
    }
    STAGE(1, 1, cur, gB, kb2);
    WAIT_VM(4);
    SBAR();
    WAIT_LGKM0();
    __builtin_amdgcn_sched_barrier(0);
    QUAD(ahi[2], ahi[3], 6, 7);
    SBAR();
  }
  WAIT_VM(0);  // drain tail stages before LDS goes away

  // epilogue: C/D layout col = lane&15, row = (lane>>4)*4 + j
  const int rbase = (lane >> 4) * 4;
#pragma unroll
  for (int c = 0; c < 4; ++c) {
    const int col = n0 + wc * 64 + c * 16 + frow;
    const float bv = bias[col];
#pragma unroll
    for (int r = 0; r < 8; ++r) {
#pragma unroll
      for (int j = 0; j < 4; ++j) {
        int row = m0 + wr * 128 + r * 16 + rbase + j;
        float v = acc[r][c][j] + bv;
        if (RELU) v = fmaxf(v, 0.f);
        C[(long)row * ldc + col] = (_Float16)v;
      }
    }
  }
#undef STAGE
#undef QUAD
}

// ---------------- batched strided f32 -> f16 convert (rows of 1024 floats) ----------------
struct CVE { const float* in; _Float16* out; long ld_in; long ld_out; long n4; };
struct CVB { CVE e[7]; };
__global__ __launch_bounds__(256) void cvt_batch(CVB a) {
  const CVE e = a.e[blockIdx.y];
  long i = (long)blockIdx.x * blockDim.x + threadIdx.x;
  long stride = (long)gridDim.x * blockDim.x;
  for (; i < e.n4; i += stride) {
    long row = i >> 8;
    long c4 = i & 255;
    float4 v = *reinterpret_cast<const float4*>(e.in + row * e.ld_in + c4 * 4);
    union { _Float16 h[4]; short4 s; } u;
    u.h[0] = (_Float16)v.x; u.h[1] = (_Float16)v.y;
    u.h[2] = (_Float16)v.z; u.h[3] = (_Float16)v.w;
    *reinterpret_cast<short4*>(e.out + row * e.ld_out + c4 * 4) = u.s;
  }
}

// ---------------- batched 1024x1024 transpose + f32->f16 ----------------
struct TP8 { const float* in[8]; _Float16* out[8]; };
__global__ __launch_bounds__(256) void transpose_cvt(TP8 args) {
  __shared__ float tile[32][33];
  const float* in = args.in[blockIdx.z];
  _Float16* out = args.out[blockIdx.z];
  const int bx = blockIdx.x * 32;
  const int by = blockIdx.y * 32;
  const int tx = threadIdx.x & 31;
  const int ty = threadIdx.x >> 5;
#pragma unroll
  for (int r = 0; r < 32; r += 8)
    tile[ty + r][tx] = in[(long)(by + ty + r) * 1024 + bx + tx];
  __syncthreads();
#pragma unroll
  for (int r = 0; r < 32; r += 8)
    out[(long)(bx + ty + r) * 1024 + by + tx] = (_Float16)tile[tx][ty + r];
}

// ---------------- batched matvec: y = W@x + add (K = kj*256 floats) ----------------
struct MVE { const float* W; const float* x; const float* add; float* y; long ld; int kj; };
struct MVB { MVE e[3]; };
__global__ __launch_bounds__(256) void matvecb(MVB a) {
  const MVE e = a.e[blockIdx.y];
  const int row = blockIdx.x * 4 + (threadIdx.x >> 6);
  const int lane = threadIdx.x & 63;
  const float* wr = e.W + (long)row * e.ld;
  float s = 0.f;
  for (int j = 0; j < e.kj; ++j) {
    float4 w4 = *reinterpret_cast<const float4*>(wr + (lane + 64 * j) * 4);
    float4 x4 = *reinterpret_cast<const float4*>(e.x + (lane + 64 * j) * 4);
    s += w4.x * x4.x + w4.y * x4.y + w4.z * x4.z + w4.w * x4.w;
  }
#pragma unroll
  for (int off = 32; off > 0; off >>= 1) s += __shfl_down(s, off);
  if (lane == 0) e.y[row] = s + (e.add ? e.add[row] : 0.f);
}

// ---------------- 128^2 GEMM (weight-combine), batched over blockIdx.y ----------------
struct GemmArgs { const _Float16* A; const _Float16* W; const float* bias; _Float16* C; int ldc; };
struct GB5 { GemmArgs g[5]; };

__global__ __launch_bounds__(256, 2) void gemm_f16(GB5 args, int M, int N, int K) {
  __shared__ __align__(16) _Float16 As[128 * 32];
  __shared__ __align__(16) _Float16 Ws[128 * 32];

  const GemmArgs ga = args.g[blockIdx.y];
  const int t = threadIdx.x;
  const int lane = t & 63;
  const int wave = t >> 6;
  const int wr = wave >> 1;
  const int wc = wave & 1;

  const int nwg = gridDim.x;
  const int bid = blockIdx.x;
  const int swz = (bid & 7) * (nwg >> 3) + (bid >> 3);
  const int nTilesN = N >> 7;
  const int m0 = (swz / nTilesN) << 7;
  const int n0 = (swz % nTilesN) << 7;

  floatx4 acc[4][4] = {};
  const int srow = t >> 2;
  const int scol = (t & 3) * 8;
  const _Float16* Ag = ga.A + (long)(m0 + srow) * K + scol;
  const _Float16* Wg = ga.W + (long)(n0 + srow) * K + scol;
  const int frow = lane & 15;
  const int fk = (lane >> 4) * 8;

  for (int k0 = 0; k0 < K; k0 += 32) {
#pragma unroll
    for (int i = 0; i < 2; ++i) {
      __builtin_amdgcn_global_load_lds(
          (const GLOBAL_AS void*)(Ag + (long)i * 64 * K + k0),
          (LDS_AS void*)(&As[i * 2048 + t * 8]), 16, 0, 0);
      __builtin_amdgcn_global_load_lds(
          (const GLOBAL_AS void*)(Wg + (long)i * 64 * K + k0),
          (LDS_AS void*)(&Ws[i * 2048 + t * 8]), 16, 0, 0);
    }
    __syncthreads();
    half8 a[4], b[4];
#pragma unroll
    for (int r = 0; r < 4; ++r)
      a[r] = *(const half8*)&As[(wr * 64 + r * 16 + frow) * 32 + fk];
#pragma unroll
    for (int c = 0; c < 4; ++c)
      b[c] = *(const half8*)&Ws[(wc * 64 + c * 16 + frow) * 32 + fk];
#pragma unroll
    for (int r = 0; r < 4; ++r)
#pragma unroll
      for (int c = 0; c < 4; ++c)
        acc[r][c] = __builtin_amdgcn_mfma_f32_16x16x32_f16(a[r], b[c], acc[r][c], 0, 0, 0);
    __syncthreads();
  }

  const int rbase = lane >> 4;
#pragma unroll
  for (int c = 0; c < 4; ++c) {
    const int col = n0 + wc * 64 + c * 16 + frow;
    const float bv = ga.bias ? ga.bias[col] : 0.f;
#pragma unroll
    for (int r = 0; r < 4; ++r)
#pragma unroll
      for (int j = 0; j < 4; ++j) {
        int row = m0 + wr * 64 + r * 16 + rbase * 4 + j;
        ga.C[(long)row * ga.ldc + col] = (_Float16)(acc[r][c][j] + bv);
      }
  }
}

// ---------------- LayerNorm (1024), f16 in, f32 out ----------------
__global__ __launch_bounds__(256) void ln_f16(const _Float16* __restrict__ x,
                                              const float* __restrict__ g,
                                              const float* __restrict__ b,
                                              float* __restrict__ out) {
  const int row = blockIdx.x;
  const int t = threadIdx.x;
  const _Float16* xr = x + (size_t)row * FDIM;
  short4 raw = reinterpret_cast<const short4*>(xr)[t];
  union { short4 s; _Float16 h[4]; } u;
  u.s = raw;
  float v0 = (float)u.h[0], v1 = (float)u.h[1], v2 = (float)u.h[2], v3 = (float)u.h[3];
  float s = v0 + v1 + v2 + v3;
  float q = v0 * v0 + v1 * v1 + v2 * v2 + v3 * v3;
#pragma unroll
  for (int off = 32; off > 0; off >>= 1) {
    s += __shfl_down(s, off);
    q += __shfl_down(q, off);
  }
  __shared__ float ss[4], qs[4];
  int wave = t >> 6, lane = t & 63;
  if (lane == 0) { ss[wave] = s; qs[wave] = q; }
  __syncthreads();
  float S = ss[0] + ss[1] + ss[2] + ss[3];
  float Q = qs[0] + qs[1] + qs[2] + qs[3];
  float mu = S * (1.f / FDIM);
  float var = Q * (1.f / FDIM) - mu * mu;
  float rs = rsqrtf(var + 1e-5f);
  int c = t * 4;
  float4 o;
  o.x = (v0 - mu) * rs * g[c + 0] + b[c + 0];
  o.y = (v1 - mu) * rs * g[c + 1] + b[c + 1];
  o.z = (v2 - mu) * rs * g[c + 2] + b[c + 2];
  o.w = (v3 - mu) * rs * g[c + 3] + b[c + 3];
  reinterpret_cast<float4*>(out + (size_t)row * FDIM)[t] = o;
}

// ---------------- launch ----------------
extern "C" void kernel_launch(void* const* d_in, const int* in_sizes, int n_in,
                              void* d_out, int out_size, void* d_ws, size_t ws_size,
                              hipStream_t stream) {
  const float* spatial  = (const float*)d_in[0];
  const float* temporal = (const float*)d_in[1];
  const float* sp_w = (const float*)d_in[2];
  const float* sp_b = (const float*)d_in[3];
  const float* tp_w = (const float*)d_in[4];
  const float* tp_b = (const float*)d_in[5];
  const float* st_vw = (const float*)d_in[10];
  const float* st_vb = (const float*)d_in[11];
  const float* st_ow = (const float*)d_in[12];
  const float* st_ob = (const float*)d_in[13];
  const float* ts_vw = (const float*)d_in[18];
  const float* ts_vb = (const float*)d_in[19];
  const float* ts_ow = (const float*)d_in[20];
  const float* ts_ob = (const float*)d_in[21];
  const float* sa_vw = (const float*)d_in[26];
  const float* sa_vb = (const float*)d_in[27];
  const float* sa_ow = (const float*)d_in[28];
  const float* sa_ob = (const float*)d_in[29];
  const float* f1_w = (const float*)d_in[30];   // (1024, 2048)
  const float* f1_b = (const float*)d_in[31];
  const float* f2_w = (const float*)d_in[32];
  const float* f2_b = (const float*)d_in[33];
  const float* ln_g = (const float*)d_in[34];
  const float* ln_b = (const float*)d_in[35];

  char* base = (char*)d_ws;
  size_t off = 0;
  auto alloc = [&](size_t bytes) { void* p = base + off; off += (bytes + 255) & ~255ull; return p; };
  const size_t W16 = 1024 * 1024 * sizeof(_Float16);

  _Float16* Xcat = (_Float16*)alloc((size_t)NB * 2048 * 2);
  _Float16* h    = (_Float16*)alloc((size_t)NB * 1024 * 2);
  _Float16* opre = (_Float16*)alloc((size_t)NB * 1024 * 2);
  _Float16* st_owT = (_Float16*)alloc(W16);
  _Float16* ts_owT = (_Float16*)alloc(W16);
  _Float16* sa_vwT = (_Float16*)alloc(W16);
  _Float16* tp_wT  = (_Float16*)alloc(W16);
  _Float16* sp_wT  = (_Float16*)alloc(W16);
  _Float16* f2_wT  = (_Float16*)alloc(W16);
  _Float16* f1a16  = (_Float16*)alloc(W16);
  _Float16* f1b16  = (_Float16*)alloc(W16);
  _Float16* sa_ow16= (_Float16*)alloc(W16);
  _Float16* st_vw16= (_Float16*)alloc(W16);
  _Float16* ts_vw16= (_Float16*)alloc(W16);
  _Float16* P1 = (_Float16*)alloc(W16);
  _Float16* Q2 = (_Float16*)alloc(W16);
  _Float16* P3 = (_Float16*)alloc(W16);
  _Float16* Q4 = (_Float16*)alloc(W16);
  _Float16* P5 = (_Float16*)alloc(W16);
  _Float16* W2 = (_Float16*)alloc(W16);
  _Float16* Wh = (_Float16*)alloc((size_t)1024 * 2048 * 2);
  float* u1 = (float*)alloc(3 * 1024 * 4);
  float* u2 = (float*)alloc(3 * 1024 * 4);   // [u2_s | u2_t | b2] contiguous
  float* bh = (float*)alloc(1024 * 4);

  // 1) all f32->f16 converts in ONE batched launch
  {
    CVB cb = {};
    cb.e[0] = { temporal, Xcat,        1024, 2048, (long)NB * 256 };
    cb.e[1] = { spatial,  Xcat + 1024, 1024, 2048, (long)NB * 256 };
    cb.e[2] = { f1_w,        f1a16,   2048, 1024, 1024 * 256 };
    cb.e[3] = { f1_w + 1024, f1b16,   2048, 1024, 1024 * 256 };
    cb.e[4] = { sa_ow,       sa_ow16, 1024, 1024, 1024 * 256 };
    cb.e[5] = { st_vw,       st_vw16, 1024, 1024, 1024 * 256 };
    cb.e[6] = { ts_vw,       ts_vw16, 1024, 1024, 1024 * 256 };
    cvt_batch<<<dim3(1024, 7), 256, 0, stream>>>(cb);
  }

  // 2) transposed f16 weights (one batched launch)
  TP8 tp = {};
  tp.in[0] = st_ow; tp.out[0] = st_owT;
  tp.in[1] = ts_ow; tp.out[1] = ts_owT;
  tp.in[2] = sa_vw; tp.out[2] = sa_vwT;
  tp.in[3] = tp_w;  tp.out[3] = tp_wT;
  tp.in[4] = sp_w;  tp.out[4] = sp_wT;
  tp.in[5] = f2_w;  tp.out[5] = f2_wT;
  transpose_cvt<<<dim3(32, 32, 6), 256, 0, stream>>>(tp);

  // 3) bias chains: u1 -> u2 -> bh (3 matvec launches)
  {
    MVB a = {};
    a.e[0] = { st_vw, tp_b, st_vb, u1,        1024, 4 };
    a.e[1] = { ts_vw, sp_b, ts_vb, u1 + 1024, 1024, 4 };
    a.e[2] = { sa_vw, f2_b, sa_vb, u1 + 2048, 1024, 4 };
    matvecb<<<dim3(256, 3), 256, 0, stream>>>(a);
  }
  {
    MVB a = {};
    a.e[0] = { st_ow, u1,        st_ob, u2,        1024, 4 };
    a.e[1] = { ts_ow, u1 + 1024, ts_ob, u2 + 1024, 1024, 4 };
    a.e[2] = { sa_ow, u1 + 2048, sa_ob, u2 + 2048, 1024, 4 };
    matvecb<<<dim3(256, 3), 256, 0, stream>>>(a);
  }
  {
    MVB a = {};   // bh = f1_w @ [u2_s; u2_t] + f1_b   (K = 2048)
    a.e[0] = { f1_w, u2, f1_b, bh, 2048, 8 };
    matvecb<<<dim3(256, 1), 256, 0, stream>>>(a);
  }

  // 4) weight tree — stage A: P1=f1a@st_ow, Q2=(st_vw@tp_w)^T, P3=f1b@ts_ow,
  //    Q4=(ts_vw@sp_w)^T, P5=sa_ow@sa_vw
  {
    GB5 g = {};
    g.g[0] = { f1a16,  st_owT, nullptr, P1, 1024 };
    g.g[1] = { tp_wT,  st_vw16, nullptr, Q2, 1024 };
    g.g[2] = { f1b16,  ts_owT, nullptr, P3, 1024 };
    g.g[3] = { sp_wT,  ts_vw16, nullptr, Q4, 1024 };
    g.g[4] = { sa_ow16, sa_vwT, nullptr, P5, 1024 };
    gemm_f16<<<dim3(64, 5), 256, 0, stream>>>(g, 1024, 1024, 1024);
  }
  // stage B: Wh_t = P1@Q2^T, Wh_s = P3@Q4^T, W2 = P5@f2_w
  {
    GB5 g = {};
    g.g[0] = { P1, Q2, nullptr, Wh,        2048 };
    g.g[1] = { P3, Q4, nullptr, Wh + 1024, 2048 };
    g.g[2] = { P5, f2_wT, nullptr, W2,     1024 };
    gemm_f16<<<dim3(64, 3), 256, 0, stream>>>(g, 1024, 1024, 1024);
  }

  // 5) big GEMMs (256^2 4-phase)
  gemm256<1><<<dim3(256), 512, 0, stream>>>(Xcat, Wh, bh, h, NB, 1024, 2048, 1024);
  gemm256<0><<<dim3(256), 512, 0, stream>>>(h, W2, u2 + 2048, opre, NB, 1024, 1024, 1024);

  // 6) LayerNorm
  ln_f16<<<NB, 256, 0, stream>>>(opre, ln_g, ln_b, (float*)d_out);
}

// Round 7
// 233.897 us; speedup vs baseline: 2.2949x; 1.0007x over previous
//
#include <hip/hip_runtime.h>
#include <hip/hip_fp16.h>

// SpatioTemporalFusion — folded to 2 big GEMMs + weight-combine tree + LN.
//   h    = relu(Xcat @ Wh^T + bh),  Xcat=[temporal|spatial] (16384x2048)
//   out  = LN(h @ W2^T + b2)
// gemm256: 256x256 tile, BK=64, 8 waves, 4-phase schedule. A-fragment ds_reads
// software-pipelined one phase ahead (ping-pong aP/aQ): each phase's lgkmcnt(0)
// drains the PREVIOUS phase's reads, so ds_read latency overlaps MFMA.
// STAGE ring {ph1:A0(t+1)->nxt, ph2:A1(t+1)->nxt, ph3:B0(t+2)->cur,
// ph4:B1(t+2)->cur}, counted vmcnt(4), read-side XOR-swizzle + pre-swizzled
// global source, setprio around MFMA.
// NOTE (r5/r6 post-mortem): f32-A reg-staging needs 128B/thread (8 GLD4), not
// 64B — the 4-GLD4 version skipped rows 8..15 mod 16. Deferred: the fix costs
// +32 VGPRs -> spill risk -> scratch vmem corrupts counted vmcnt.

typedef _Float16 half8 __attribute__((ext_vector_type(8)));
typedef float floatx4 __attribute__((ext_vector_type(4)));

#define GLOBAL_AS __attribute__((address_space(1)))
#define LDS_AS __attribute__((address_space(3)))

#define NB 16384
#define FDIM 1024

#define SBAR() asm volatile("s_barrier" ::: "memory")
#define WAIT_LGKM0() asm volatile("s_waitcnt lgkmcnt(0)" ::: "memory")
#define WAIT_VM(n) asm volatile("s_waitcnt vmcnt(" #n ")" ::: "memory")
#define SB0() __builtin_amdgcn_sched_barrier(0)
#define DSREAD(dst, addr) asm volatile("ds_read_b128 %0, %1" : "=v"(dst) : "v"(addr))

// ---------------- 256^2 pipelined 4-phase GEMM: C = A@W^T + bias (opt relu) ----------------
template <int RELU>
__global__ __launch_bounds__(512, 2) void gemm256(
    const _Float16* __restrict__ A, const _Float16* __restrict__ W,
    const float* __restrict__ bias, _Float16* __restrict__ C,
    int M, int N, int K, int ldc) {
  __shared__ __align__(16) _Float16 smem[2 * 2 * 256 * 64];  // 128 KiB

  const int t = threadIdx.x;
  const int lane = t & 63;
  const int w = t >> 6;        // wave 0..7
  const int wr = w >> 2;       // 0..1 -> 128-row slab
  const int wc = w & 3;        // 0..3 -> 64-col slab

  const int nwg = gridDim.x;
  const int bid = blockIdx.x;
  const int swz = (bid & 7) * (nwg >> 3) + (bid >> 3);
  const int nTN = N >> 8;
  const int m0 = (swz / nTN) << 8;
  const int n0 = (swz % nTN) << 8;
  const int NT = K >> 6;       // BK=64 K-tiles (>=2 here)

  // staging: half-tile = 128 rows x 64 cols (16 KiB); pre-swizzled global source
  const int srow = w * 16 + (lane >> 3);
  const int scs = (lane & 7) ^ ((lane >> 3) & 7);
  const char* gA = (const char*)(A + (long)(m0 + srow) * K + scs * 8);
  const char* gB = (const char*)(W + (long)(n0 + srow) * K + scs * 8);
  const long dJ = (long)K * 16;    // +8 rows
  const long dH = (long)K * 256;   // +128 rows
  const int ldst = w * 2048 + lane * 16;

  // fragment reads: swizzled LDS byte addresses
  unsigned sb = (unsigned)(unsigned long long)(LDS_AS void*)smem;
  const int frow = lane & 15;
  const unsigned offk = (unsigned)((((lane >> 4) * 16) ^ ((frow & 7) << 4)));
  const unsigned aoff = (unsigned)((wr * 128 + frow) * 128);
  const unsigned boff = (unsigned)(32768 + (wc * 64 + frow) * 128);

  floatx4 acc[8][4] = {};
  half8 b[4][2], aP[2][2], aQ[2][2];

#define STAGE(ab, hf, buf, gp, kb)                                               \
  do {                                                                           \
    const char* _s = (gp) + (hf) * dH + (kb);                                    \
    char* _d = (char*)smem + (buf) * 65536 + (ab) * 32768 + (hf) * 16384 + ldst; \
    __builtin_amdgcn_global_load_lds((const GLOBAL_AS void*)_s,                  \
                                     (LDS_AS void*)_d, 16, 0, 0);                \
    __builtin_amdgcn_global_load_lds((const GLOBAL_AS void*)(_s + dJ),           \
                                     (LDS_AS void*)(_d + 1024), 16, 0, 0);       \
  } while (0)

#define RD_B()                                                                    \
  do {                                                                            \
    _Pragma("unroll") for (int c = 0; c < 4; ++c) {                               \
      DSREAD(b[c][0], baseB + c * 2048 + offk);                                   \
      DSREAD(b[c][1], baseB + c * 2048 + (offk ^ 64u));                           \
    }                                                                             \
  } while (0)

#define RD_A(S, r, ba)                                                            \
  do {                                                                            \
    DSREAD(S[0][0], (ba) + (r) * 2048 + offk);                                    \
    DSREAD(S[0][1], (ba) + (r) * 2048 + (offk ^ 64u));                            \
    DSREAD(S[1][0], (ba) + (r + 1) * 2048 + offk);                                \
    DSREAD(S[1][1], (ba) + (r + 1) * 2048 + (offk ^ 64u));                        \
  } while (0)

#define QUAD(S, i0, i1)                                                                     \
  do {                                                                                      \
    __builtin_amdgcn_s_setprio(1);                                                          \
    _Pragma("unroll") for (int c = 0; c < 4; ++c) {                                         \
      acc[i0][c] = __builtin_amdgcn_mfma_f32_16x16x32_f16(S[0][0], b[c][0], acc[i0][c], 0, 0, 0); \
      acc[i0][c] = __builtin_amdgcn_mfma_f32_16x16x32_f16(S[0][1], b[c][1], acc[i0][c], 0, 0, 0); \
      acc[i1][c] = __builtin_amdgcn_mfma_f32_16x16x32_f16(S[1][0], b[c][0], acc[i1][c], 0, 0, 0); \
      acc[i1][c] = __builtin_amdgcn_mfma_f32_16x16x32_f16(S[1][1], b[c][1], acc[i1][c], 0, 0, 0); \
    }                                                                                       \
    __builtin_amdgcn_s_setprio(0);                                                          \
  } while (0)

  // prologue: tile0 {A0,A1,B0,B1}->buf0, tile1 {B0,B1}->buf1; vmcnt(4) => tile0 resident
  {
    const long k1 = 128L;  // NT >= 2
    STAGE(0, 0, 0, gA, 0); STAGE(0, 1, 0, gA, 0);
    STAGE(1, 0, 0, gB, 0); STAGE(1, 1, 0, gB, 0);
    STAGE(1, 0, 1, gB, k1); STAGE(1, 1, 1, gB, k1);
  }
  WAIT_VM(4);
  SBAR();
  RD_A(aP, 0, sb + aoff);  // read-ahead: tile0 quadrant0

  for (int kt = 0; kt < NT; ++kt) {
    const int cur = kt & 1, nxt = cur ^ 1;
    const unsigned baseA = sb + (unsigned)(cur * 65536) + aoff;
    const unsigned baseAn = sb + (unsigned)(nxt * 65536) + aoff;
    const unsigned baseB = sb + (unsigned)(cur * 65536) + boff;
    const long kb1 = (long)(kt + 1 < NT ? kt + 1 : NT - 1) * 128;
    const long kb2 = (long)(kt + 2 < NT ? kt + 2 : NT - 1) * 128;

    // ph1: B-frag reads; stage A0(t+1)->nxt (A-nxt dead since t-1)
    RD_B();
    STAGE(0, 0, nxt, gA, kb1);
    SBAR(); WAIT_LGKM0();      // drains RD_B + read-ahead aP(q0)
    RD_A(aQ, 2, baseA);        // issue q1 (overlaps q0 MFMA)
    SB0();
    QUAD(aP, 0, 1);
    SBAR();

    // ph2: stage A1(t+1)->nxt
    STAGE(0, 1, nxt, gA, kb1);
    SBAR(); WAIT_LGKM0();      // drains aQ(q1)
    RD_A(aP, 4, baseA);        // issue q2
    SB0();
    QUAD(aQ, 2, 3);
    SBAR();

    // ph3: stage B0(t+2)->cur (B-cur dead since ph1)
    STAGE(1, 0, cur, gB, kb2);
    SBAR(); WAIT_LGKM0();      // drains aP(q2)
    RD_A(aQ, 6, baseA);        // issue q3
    SB0();
    QUAD(aP, 4, 5);
    SBAR();

    // ph4: stage B1(t+2)->cur; vmcnt(4) => A(t+1),B(t+1) resident
    STAGE(1, 1, cur, gB, kb2);
    WAIT_VM(4);
    SBAR(); WAIT_LGKM0();      // drains aQ(q3)
    RD_A(aP, 0, baseAn);       // read-ahead: quadrant0 of tile t+1
    SB0();
    QUAD(aQ, 6, 7);
    SBAR();
  }
  WAIT_VM(0);
  WAIT_LGKM0();   // drain dangling read-ahead

  // epilogue: C/D layout col = lane&15, row = (lane>>4)*4 + j
  const int rbase = (lane >> 4) * 4;
#pragma unroll
  for (int c = 0; c < 4; ++c) {
    const int col = n0 + wc * 64 + c * 16 + frow;
    const float bv = bias[col];
#pragma unroll
    for (int r = 0; r < 8; ++r) {
#pragma unroll
      for (int j = 0; j < 4; ++j) {
        int row = m0 + wr * 128 + r * 16 + rbase + j;
        float v = acc[r][c][j] + bv;
        if (RELU) v = fmaxf(v, 0.f);
        C[(long)row * ldc + col] = (_Float16)v;
      }
    }
  }
#undef STAGE
#undef RD_B
#undef RD_A
#undef QUAD
}

// ---------------- batched strided f32 -> f16 convert (rows of 1024 floats) ----------------
struct CVE { const float* in; _Float16* out; long ld_in; long ld_out; long n4; };
struct CVB { CVE e[7]; };
__global__ __launch_bounds__(256) void cvt_batch(CVB a) {
  const CVE e = a.e[blockIdx.y];
  long i = (long)blockIdx.x * blockDim.x + threadIdx.x;
  long stride = (long)gridDim.x * blockDim.x;
  for (; i < e.n4; i += stride) {
    long row = i >> 8;
    long c4 = i & 255;
    float4 v = *reinterpret_cast<const float4*>(e.in + row * e.ld_in + c4 * 4);
    union { _Float16 h[4]; short4 s; } u;
    u.h[0] = (_Float16)v.x; u.h[1] = (_Float16)v.y;
    u.h[2] = (_Float16)v.z; u.h[3] = (_Float16)v.w;
    *reinterpret_cast<short4*>(e.out + row * e.ld_out + c4 * 4) = u.s;
  }
}

// ---------------- batched 1024x1024 transpose + f32->f16 ----------------
struct TP8 { const float* in[8]; _Float16* out[8]; };
__global__ __launch_bounds__(256) void transpose_cvt(TP8 args) {
  __shared__ float tile[32][33];
  const float* in = args.in[blockIdx.z];
  _Float16* out = args.out[blockIdx.z];
  const int bx = blockIdx.x * 32;
  const int by = blockIdx.y * 32;
  const int tx = threadIdx.x & 31;
  const int ty = threadIdx.x >> 5;
#pragma unroll
  for (int r = 0; r < 32; r += 8)
    tile[ty + r][tx] = in[(long)(by + ty + r) * 1024 + bx + tx];
  __syncthreads();
#pragma unroll
  for (int r = 0; r < 32; r += 8)
    out[(long)(bx + ty + r) * 1024 + by + tx] = (_Float16)tile[tx][ty + r];
}

// ---------------- batched matvec: y = W@x + add (K = kj*256 floats) ----------------
struct MVE { const float* W; const float* x; const float* add; float* y; long ld; int kj; };
struct MVB { MVE e[3]; };
__global__ __launch_bounds__(256) void matvecb(MVB a) {
  const MVE e = a.e[blockIdx.y];
  const int row = blockIdx.x * 4 + (threadIdx.x >> 6);
  const int lane = threadIdx.x & 63;
  const float* wr = e.W + (long)row * e.ld;
  float s = 0.f;
  for (int j = 0; j < e.kj; ++j) {
    float4 w4 = *reinterpret_cast<const float4*>(wr + (lane + 64 * j) * 4);
    float4 x4 = *reinterpret_cast<const float4*>(e.x + (lane + 64 * j) * 4);
    s += w4.x * x4.x + w4.y * x4.y + w4.z * x4.z + w4.w * x4.w;
  }
#pragma unroll
  for (int off = 32; off > 0; off >>= 1) s += __shfl_down(s, off);
  if (lane == 0) e.y[row] = s + (e.add ? e.add[row] : 0.f);
}

// ---------------- 128^2 GEMM (weight-combine), batched over blockIdx.y ----------------
struct GemmArgs { const _Float16* A; const _Float16* W; const float* bias; _Float16* C; int ldc; };
struct GB5 { GemmArgs g[5]; };

__global__ __launch_bounds__(256, 2) void gemm_f16(GB5 args, int M, int N, int K) {
  __shared__ __align__(16) _Float16 As[128 * 32];
  __shared__ __align__(16) _Float16 Ws[128 * 32];

  const GemmArgs ga = args.g[blockIdx.y];
  const int t = threadIdx.x;
  const int lane = t & 63;
  const int wave = t >> 6;
  const int wr = wave >> 1;
  const int wc = wave & 1;

  const int nwg = gridDim.x;
  const int bid = blockIdx.x;
  const int swz = (bid & 7) * (nwg >> 3) + (bid >> 3);
  const int nTilesN = N >> 7;
  const int m0 = (swz / nTilesN) << 7;
  const int n0 = (swz % nTilesN) << 7;

  floatx4 acc[4][4] = {};
  const int srow = t >> 2;
  const int scol = (t & 3) * 8;
  const _Float16* Ag = ga.A + (long)(m0 + srow) * K + scol;
  const _Float16* Wg = ga.W + (long)(n0 + srow) * K + scol;
  const int frow = lane & 15;
  const int fk = (lane >> 4) * 8;

  for (int k0 = 0; k0 < K; k0 += 32) {
#pragma unroll
    for (int i = 0; i < 2; ++i) {
      __builtin_amdgcn_global_load_lds(
          (const GLOBAL_AS void*)(Ag + (long)i * 64 * K + k0),
          (LDS_AS void*)(&As[i * 2048 + t * 8]), 16, 0, 0);
      __builtin_amdgcn_global_load_lds(
          (const GLOBAL_AS void*)(Wg + (long)i * 64 * K + k0),
          (LDS_AS void*)(&Ws[i * 2048 + t * 8]), 16, 0, 0);
    }
    __syncthreads();
    half8 a[4], b[4];
#pragma unroll
    for (int r = 0; r < 4; ++r)
      a[r] = *(const half8*)&As[(wr * 64 + r * 16 + frow) * 32 + fk];
#pragma unroll
    for (int c = 0; c < 4; ++c)
      b[c] = *(const half8*)&Ws[(wc * 64 + c * 16 + frow) * 32 + fk];
#pragma unroll
    for (int r = 0; r < 4; ++r)
#pragma unroll
      for (int c = 0; c < 4; ++c)
        acc[r][c] = __builtin_amdgcn_mfma_f32_16x16x32_f16(a[r], b[c], acc[r][c], 0, 0, 0);
    __syncthreads();
  }

  const int rbase = lane >> 4;
#pragma unroll
  for (int c = 0; c < 4; ++c) {
    const int col = n0 + wc * 64 + c * 16 + frow;
    const float bv = ga.bias ? ga.bias[col] : 0.f;
#pragma unroll
    for (int r = 0; r < 4; ++r)
#pragma unroll
      for (int j = 0; j < 4; ++j) {
        int row = m0 + wr * 64 + r * 16 + rbase * 4 + j;
        ga.C[(long)row * ga.ldc + col] = (_Float16)(acc[r][c][j] + bv);
      }
  }
}

// ---------------- LayerNorm (1024), f16 in, f32 out ----------------
__global__ __launch_bounds__(256) void ln_f16(const _Float16* __restrict__ x,
                                              const float* __restrict__ g,
                                              const float* __restrict__ b,
                                              float* __restrict__ out) {
  const int row = blockIdx.x;
  const int t = threadIdx.x;
  const _Float16* xr = x + (size_t)row * FDIM;
  short4 raw = reinterpret_cast<const short4*>(xr)[t];
  union { short4 s; _Float16 h[4]; } u;
  u.s = raw;
  float v0 = (float)u.h[0], v1 = (float)u.h[1], v2 = (float)u.h[2], v3 = (float)u.h[3];
  float s = v0 + v1 + v2 + v3;
  float q = v0 * v0 + v1 * v1 + v2 * v2 + v3 * v3;
#pragma unroll
  for (int off = 32; off > 0; off >>= 1) {
    s += __shfl_down(s, off);
    q += __shfl_down(q, off);
  }
  __shared__ float ss[4], qs[4];
  int wave = t >> 6, lane = t & 63;
  if (lane == 0) { ss[wave] = s; qs[wave] = q; }
  __syncthreads();
  float S = ss[0] + ss[1] + ss[2] + ss[3];
  float Q = qs[0] + qs[1] + qs[2] + qs[3];
  float mu = S * (1.f / FDIM);
  float var = Q * (1.f / FDIM) - mu * mu;
  float rs = rsqrtf(var + 1e-5f);
  int c = t * 4;
  float4 o;
  o.x = (v0 - mu) * rs * g[c + 0] + b[c + 0];
  o.y = (v1 - mu) * rs * g[c + 1] + b[c + 1];
  o.z = (v2 - mu) * rs * g[c + 2] + b[c + 2];
  o.w = (v3 - mu) * rs * g[c + 3] + b[c + 3];
  reinterpret_cast<float4*>(out + (size_t)row * FDIM)[t] = o;
}

// ---------------- launch ----------------
extern "C" void kernel_launch(void* const* d_in, const int* in_sizes, int n_in,
                              void* d_out, int out_size, void* d_ws, size_t ws_size,
                              hipStream_t stream) {
  const float* spatial  = (const float*)d_in[0];
  const float* temporal = (const float*)d_in[1];
  const float* sp_w = (const float*)d_in[2];
  const float* sp_b = (const float*)d_in[3];
  const float* tp_w = (const float*)d_in[4];
  const float* tp_b = (const float*)d_in[5];
  const float* st_vw = (const float*)d_in[10];
  const float* st_vb = (const float*)d_in[11];
  const float* st_ow = (const float*)d_in[12];
  const float* st_ob = (const float*)d_in[13];
  const float* ts_vw = (const float*)d_in[18];
  const float* ts_vb = (const float*)d_in[19];
  const float* ts_ow = (const float*)d_in[20];
  const float* ts_ob = (const float*)d_in[21];
  const float* sa_vw = (const float*)d_in[26];
  const float* sa_vb = (const float*)d_in[27];
  const float* sa_ow = (const float*)d_in[28];
  const float* sa_ob = (const float*)d_in[29];
  const float* f1_w = (const float*)d_in[30];   // (1024, 2048)
  const float* f1_b = (const float*)d_in[31];
  const float* f2_w = (const float*)d_in[32];
  const float* f2_b = (const float*)d_in[33];
  const float* ln_g = (const float*)d_in[34];
  const float* ln_b = (const float*)d_in[35];

  char* base = (char*)d_ws;
  size_t off = 0;
  auto alloc = [&](size_t bytes) { void* p = base + off; off += (bytes + 255) & ~255ull; return p; };
  const size_t W16 = 1024 * 1024 * sizeof(_Float16);

  _Float16* Xcat = (_Float16*)alloc((size_t)NB * 2048 * 2);
  _Float16* h    = (_Float16*)alloc((size_t)NB * 1024 * 2);
  _Float16* opre = (_Float16*)alloc((size_t)NB * 1024 * 2);
  _Float16* st_owT = (_Float16*)alloc(W16);
  _Float16* ts_owT = (_Float16*)alloc(W16);
  _Float16* sa_vwT = (_Float16*)alloc(W16);
  _Float16* tp_wT  = (_Float16*)alloc(W16);
  _Float16* sp_wT  = (_Float16*)alloc(W16);
  _Float16* f2_wT  = (_Float16*)alloc(W16);
  _Float16* f1a16  = (_Float16*)alloc(W16);
  _Float16* f1b16  = (_Float16*)alloc(W16);
  _Float16* sa_ow16= (_Float16*)alloc(W16);
  _Float16* st_vw16= (_Float16*)alloc(W16);
  _Float16* ts_vw16= (_Float16*)alloc(W16);
  _Float16* P1 = (_Float16*)alloc(W16);
  _Float16* Q2 = (_Float16*)alloc(W16);
  _Float16* P3 = (_Float16*)alloc(W16);
  _Float16* Q4 = (_Float16*)alloc(W16);
  _Float16* P5 = (_Float16*)alloc(W16);
  _Float16* W2 = (_Float16*)alloc(W16);
  _Float16* Wh = (_Float16*)alloc((size_t)1024 * 2048 * 2);
  float* u1 = (float*)alloc(3 * 1024 * 4);
  float* u2 = (float*)alloc(3 * 1024 * 4);   // [u2_s | u2_t | b2] contiguous
  float* bh = (float*)alloc(1024 * 4);

  // 1) all f32->f16 converts in ONE batched launch
  {
    CVB cb = {};
    cb.e[0] = { temporal, Xcat,        1024, 2048, (long)NB * 256 };
    cb.e[1] = { spatial,  Xcat + 1024, 1024, 2048, (long)NB * 256 };
    cb.e[2] = { f1_w,        f1a16,   2048, 1024, 1024 * 256 };
    cb.e[3] = { f1_w + 1024, f1b16,   2048, 1024, 1024 * 256 };
    cb.e[4] = { sa_ow,       sa_ow16, 1024, 1024, 1024 * 256 };
    cb.e[5] = { st_vw,       st_vw16, 1024, 1024, 1024 * 256 };
    cb.e[6] = { ts_vw,       ts_vw16, 1024, 1024, 1024 * 256 };
    cvt_batch<<<dim3(1024, 7), 256, 0, stream>>>(cb);
  }

  // 2) transposed f16 weights (one batched launch)
  TP8 tp = {};
  tp.in[0] = st_ow; tp.out[0] = st_owT;
  tp.in[1] = ts_ow; tp.out[1] = ts_owT;
  tp.in[2] = sa_vw; tp.out[2] = sa_vwT;
  tp.in[3] = tp_w;  tp.out[3] = tp_wT;
  tp.in[4] = sp_w;  tp.out[4] = sp_wT;
  tp.in[5] = f2_w;  tp.out[5] = f2_wT;
  transpose_cvt<<<dim3(32, 32, 6), 256, 0, stream>>>(tp);

  // 3) bias chains: u1 -> u2 -> bh
  {
    MVB a = {};
    a.e[0] = { st_vw, tp_b, st_vb, u1,        1024, 4 };
    a.e[1] = { ts_vw, sp_b, ts_vb, u1 + 1024, 1024, 4 };
    a.e[2] = { sa_vw, f2_b, sa_vb, u1 + 2048, 1024, 4 };
    matvecb<<<dim3(256, 3), 256, 0, stream>>>(a);
  }
  {
    MVB a = {};
    a.e[0] = { st_ow, u1,        st_ob, u2,        1024, 4 };
    a.e[1] = { ts_ow, u1 + 1024, ts_ob, u2 + 1024, 1024, 4 };
    a.e[2] = { sa_ow, u1 + 2048, sa_ob, u2 + 2048, 1024, 4 };
    matvecb<<<dim3(256, 3), 256, 0, stream>>>(a);
  }
  {
    MVB a = {};   // bh = f1_w @ [u2_s; u2_t] + f1_b   (K = 2048)
    a.e[0] = { f1_w, u2, f1_b, bh, 2048, 8 };
    matvecb<<<dim3(256, 1), 256, 0, stream>>>(a);
  }

  // 4) weight tree — stage A: P1=f1a@st_ow, Q2=(st_vw@tp_w)^T, P3=f1b@ts_ow,
  //    Q4=(ts_vw@sp_w)^T, P5=sa_ow@sa_vw
  {
    GB5 g = {};
    g.g[0] = { f1a16,  st_owT, nullptr, P1, 1024 };
    g.g[1] = { tp_wT,  st_vw16, nullptr, Q2, 1024 };
    g.g[2] = { f1b16,  ts_owT, nullptr, P3, 1024 };
    g.g[3] = { sp_wT,  ts_vw16, nullptr, Q4, 1024 };
    g.g[4] = { sa_ow16, sa_vwT, nullptr, P5, 1024 };
    gemm_f16<<<dim3(64, 5), 256, 0, stream>>>(g, 1024, 1024, 1024);
  }
  // stage B: Wh_t = P1@Q2^T, Wh_s = P3@Q4^T, W2 = P5@f2_w
  {
    GB5 g = {};
    g.g[0] = { P1, Q2, nullptr, Wh,        2048 };
    g.g[1] = { P3, Q4, nullptr, Wh + 1024, 2048 };
    g.g[2] = { P5, f2_wT, nullptr, W2,     1024 };
    gemm_f16<<<dim3(64, 3), 256, 0, stream>>>(g, 1024, 1024, 1024);
  }

  // 5) big GEMMs (256^2 pipelined 4-phase)
  gemm256<1><<<dim3(256), 512, 0, stream>>>(Xcat, Wh, bh, h, NB, 1024, 2048, 1024);
  gemm256<0><<<dim3(256), 512, 0, stream>>>(h, W2, u2 + 2048, opre, NB, 1024, 1024, 1024);

  // 6) LayerNorm
  ln_f16<<<NB, 256, 0, stream>>>(opre, ln_g, ln_b, (float*)d_out);
}